// Round 8
// baseline (513.087 us; speedup 1.0000x reference)
//
#include <hip/hip_runtime.h>
#include <hip/hip_cooperative_groups.h>

namespace cg = cooperative_groups;

typedef unsigned short u16;
typedef unsigned int u32;
typedef __attribute__((ext_vector_type(8))) short short8;
typedef __attribute__((ext_vector_type(4))) float f32x4;

#define D_MODEL 768
#define D_INNER 1536
#define D_XZ    3072
#define D_STATE 16
#define DT_RANK 48
#define NROW    2048   // B*T
#define SEQ     1024
#define XDS     128    // padded x_dbl row stride (48 dt_r | 16 B | 16 C | pad)
#define NCHUNK  64
#define CLEN    16     // SEQ / NCHUNK

typedef const __attribute__((address_space(1))) u32 glb_u32;
typedef __attribute__((address_space(3))) u32 lds_u32;

__device__ __forceinline__ float bf2f(u16 u) {
    union { unsigned int i; float f; } v; v.i = ((unsigned int)u) << 16; return v.f;
}
__device__ __forceinline__ u16 f2bf(float f) {
    union { float f; unsigned int i; } v; v.f = f;
    unsigned int r = v.i + 0x7fffu + ((v.i >> 16) & 1u);
    return (u16)(r >> 16);
}
__device__ __forceinline__ void g2lds16(const u16* g, u16* l) {
    __builtin_amdgcn_global_load_lds((glb_u32*)g, (lds_u32*)l, 16, 0, 0);
}

// ======== fused prep: LayerNorm (blocks 0..2047) + weight prep/zeroing =====
#define N0 (D_XZ * D_MODEL / 4)        // 589824  Win->bf16
#define N1 (D_MODEL * D_INNER / 4)     // 294912  Wout->bf16
#define N2 (XDS * D_INNER / 4)         // 49152   Wxp pad128->bf16
#define N3 (D_INNER * 64 / 4)          // 24576   Wdt pad64->bf16
#define N4 (D_INNER * D_STATE / 4)     // 6144    negA
#define N5 (NROW * XDS / 4)            // 65536   zero xdbl
#define N6 (NROW * D_MODEL / 4)        // 393216  zero out
#define PREP_BLOCKS ((N0+N1+N2+N3+N4+N5+N6) / 256)   // 5560
__global__ __launch_bounds__(256) void prep_ln_k(
    const float* __restrict__ x, const float* __restrict__ g,
    const float* __restrict__ bln, u16* __restrict__ h,
    const float* __restrict__ W_in, const float* __restrict__ W_out,
    const float* __restrict__ W_xp, const float* __restrict__ W_dt,
    const float* __restrict__ A_log,
    u16* __restrict__ Win_bf, u16* __restrict__ Wout_bf,
    u16* __restrict__ Wxp_bf, u16* __restrict__ Wdt_bf,
    float* __restrict__ negA, float* __restrict__ xdbl,
    float* __restrict__ outz)
{
    __shared__ float sred[4], sqred[4];
    int tid = threadIdx.x;
    if (blockIdx.x < NROW) {
        int row = blockIdx.x;
        const float* xr = x + (size_t)row * D_MODEL;
        float v[3], s = 0.f, sq = 0.f;
#pragma unroll
        for (int j = 0; j < 3; ++j) {
            v[j] = xr[tid + j * 256];
            s += v[j]; sq += v[j] * v[j];
        }
#pragma unroll
        for (int off = 32; off >= 1; off >>= 1) {
            s  += __shfl_xor(s,  off, 64);
            sq += __shfl_xor(sq, off, 64);
        }
        if ((tid & 63) == 0) { sred[tid >> 6] = s; sqred[tid >> 6] = sq; }
        __syncthreads();
        float st = sred[0] + sred[1] + sred[2] + sred[3];
        float sqt = sqred[0] + sqred[1] + sqred[2] + sqred[3];
        float mu = st * (1.f / D_MODEL);
        float var = sqt * (1.f / D_MODEL) - mu * mu;
        float rstd = rsqrtf(var + 1e-5f);
        u16* hr = h + (size_t)row * D_MODEL;
#pragma unroll
        for (int j = 0; j < 3; ++j) {
            int idx = tid + j * 256;
            hr[idx] = f2bf((v[j] - mu) * rstd * g[idx] + bln[idx]);
        }
        return;
    }
    int gid = (blockIdx.x - NROW) * 256 + tid;
    if (gid < N0) {
        float4 v = *(const float4*)(W_in + (size_t)gid * 4);
        u16* o = Win_bf + (size_t)gid * 4;
        o[0]=f2bf(v.x); o[1]=f2bf(v.y); o[2]=f2bf(v.z); o[3]=f2bf(v.w);
    } else if (gid < N0 + N1) {
        int i = gid - N0;
        float4 v = *(const float4*)(W_out + (size_t)i * 4);
        u16* o = Wout_bf + (size_t)i * 4;
        o[0]=f2bf(v.x); o[1]=f2bf(v.y); o[2]=f2bf(v.z); o[3]=f2bf(v.w);
    } else if (gid < N0 + N1 + N2) {
        int i = gid - N0 - N1;
        int n = (i * 4) / D_INNER, k = (i * 4) % D_INNER;
        u16* o = Wxp_bf + (size_t)i * 4;
        if (n < 80) {
            float4 v = *(const float4*)(W_xp + (size_t)n * D_INNER + k);
            o[0]=f2bf(v.x); o[1]=f2bf(v.y); o[2]=f2bf(v.z); o[3]=f2bf(v.w);
        } else { o[0]=0; o[1]=0; o[2]=0; o[3]=0; }
    } else if (gid < N0 + N1 + N2 + N3) {
        int i = gid - N0 - N1 - N2;
        int r = (i * 4) >> 6, c0 = (i * 4) & 63;
        u16* o = Wdt_bf + (size_t)i * 4;
        if (c0 < DT_RANK) {
            float4 v = *(const float4*)(W_dt + (size_t)r * DT_RANK + c0);
            o[0]=f2bf(v.x); o[1]=f2bf(v.y); o[2]=f2bf(v.z); o[3]=f2bf(v.w);
        } else { o[0]=0; o[1]=0; o[2]=0; o[3]=0; }
    } else if (gid < N0 + N1 + N2 + N3 + N4) {
        int i = gid - N0 - N1 - N2 - N3;
        float4 v = *(const float4*)(A_log + (size_t)i * 4);
        *(float4*)(negA + (size_t)i * 4) =
            make_float4(-__expf(v.x), -__expf(v.y), -__expf(v.z), -__expf(v.w));
    } else if (gid < N0 + N1 + N2 + N3 + N4 + N5) {
        int i = gid - N0 - N1 - N2 - N3 - N4;
        *(float4*)(xdbl + (size_t)i * 4) = make_float4(0.f, 0.f, 0.f, 0.f);
    } else {
        int i = gid - N0 - N1 - N2 - N3 - N4 - N5;
        *(float4*)(outz + (size_t)i * 4) = make_float4(0.f, 0.f, 0.f, 0.f);
    }
}

// ============ m97-style MFMA GEMM: C(MxN) = A(MxK) * B(NxK)^T ==============
template<int MT, int NT, bool OUT_BF16>
__global__ __launch_bounds__(256) void gemm128(
    const u16* __restrict__ A, const u16* __restrict__ B,
    void* __restrict__ Cv, int M, int N, int K)
{
    constexpr int BM = 32 * MT, BN = 32 * NT;
    __shared__ __align__(16) u16 As[BM * 32];
    __shared__ __align__(16) u16 Bs[BN * 32];
    int tid = threadIdx.x, w = tid >> 6, lane = tid & 63;
    int wm = w & 1, wn = w >> 1;
    int m0 = blockIdx.x * BM, n0 = blockIdx.y * BN;
    int mloc = lane & 15, quad = lane >> 4;
    int lr = lane >> 2, lc = lane & 3;
    f32x4 acc[MT][NT] = {};

    for (int k0 = 0; k0 < K; k0 += 32) {
        __syncthreads();
#pragma unroll
        for (int j = w; j < 2 * MT; j += 4) {
            int row = j * 16 + lr;
            int cb = lc ^ ((row >> 1) & 3);
            g2lds16(A + (size_t)(m0 + row) * K + k0 + cb * 8, &As[j * 512]);
        }
#pragma unroll
        for (int j = w; j < 2 * NT; j += 4) {
            int row = j * 16 + lr;
            int cb = lc ^ ((row >> 1) & 3);
            g2lds16(B + (size_t)(n0 + row) * K + k0 + cb * 8, &Bs[j * 512]);
        }
        __syncthreads();
        short8 afr[MT], bfr[NT];
#pragma unroll
        for (int mt = 0; mt < MT; ++mt) {
            int row = wm * MT * 16 + mt * 16 + mloc;
            int cb = quad ^ ((row >> 1) & 3);
            afr[mt] = *(const short8*)(&As[row * 32 + cb * 8]);
        }
#pragma unroll
        for (int nt = 0; nt < NT; ++nt) {
            int row = wn * NT * 16 + nt * 16 + mloc;
            int cb = quad ^ ((row >> 1) & 3);
            bfr[nt] = *(const short8*)(&Bs[row * 32 + cb * 8]);
        }
#pragma unroll
        for (int mt = 0; mt < MT; ++mt)
#pragma unroll
            for (int nt = 0; nt < NT; ++nt)
                acc[mt][nt] = __builtin_amdgcn_mfma_f32_16x16x32_bf16(
                    afr[mt], bfr[nt], acc[mt][nt], 0, 0, 0);
    }
    // C/D layout: col = lane&15, row = quad*4 + reg  [verified m89/m91]
#pragma unroll
    for (int mt = 0; mt < MT; ++mt) {
        int grow0 = m0 + wm * MT * 16 + mt * 16 + quad * 4;
#pragma unroll
        for (int nt = 0; nt < NT; ++nt) {
            int gcol = n0 + wn * NT * 16 + nt * 16 + mloc;
#pragma unroll
            for (int r = 0; r < 4; ++r) {
                size_t idx = (size_t)(grow0 + r) * N + gcol;
                float v = acc[mt][nt][r];
                if (OUT_BF16) ((u16*)Cv)[idx] = f2bf(v);
                else          ((float*)Cv)[idx] = v;
            }
        }
    }
}

// ---------- split-K MFMA GEMM, f32 atomic-add epilogue ---------------------
template<int MT, int NT, int KSLICE, bool ADD_X>
__global__ __launch_bounds__(256) void gemm_splitk(
    const u16* __restrict__ A, const u16* __restrict__ B,
    const float* __restrict__ X, float* __restrict__ Cout, int K, int CS)
{
    constexpr int BM = 32 * MT, BN = 32 * NT;
    __shared__ __align__(16) u16 As[BM * 32];
    __shared__ __align__(16) u16 Bs[BN * 32];
    int tid = threadIdx.x, w = tid >> 6, lane = tid & 63;
    int wm = w & 1, wn = w >> 1;
    int m0 = blockIdx.x * BM, n0 = blockIdx.y * BN;
    int kbase = blockIdx.z * KSLICE;
    int mloc = lane & 15, quad = lane >> 4;
    int lr = lane >> 2, lc = lane & 3;
    f32x4 acc[MT][NT] = {};

    for (int k0 = 0; k0 < KSLICE; k0 += 32) {
        __syncthreads();
#pragma unroll
        for (int j = w; j < 2 * MT; j += 4) {
            int row = j * 16 + lr;
            int cb = lc ^ ((row >> 1) & 3);
            g2lds16(A + (size_t)(m0 + row) * K + kbase + k0 + cb * 8, &As[j * 512]);
        }
#pragma unroll
        for (int j = w; j < 2 * NT; j += 4) {
            int row = j * 16 + lr;
            int cb = lc ^ ((row >> 1) & 3);
            g2lds16(B + (size_t)(n0 + row) * K + kbase + k0 + cb * 8, &Bs[j * 512]);
        }
        __syncthreads();
        short8 afr[MT], bfr[NT];
#pragma unroll
        for (int mt = 0; mt < MT; ++mt) {
            int row = wm * MT * 16 + mt * 16 + mloc;
            int cb = quad ^ ((row >> 1) & 3);
            afr[mt] = *(const short8*)(&As[row * 32 + cb * 8]);
        }
#pragma unroll
        for (int nt = 0; nt < NT; ++nt) {
            int row = wn * NT * 16 + nt * 16 + mloc;
            int cb = quad ^ ((row >> 1) & 3);
            bfr[nt] = *(const short8*)(&Bs[row * 32 + cb * 8]);
        }
#pragma unroll
        for (int mt = 0; mt < MT; ++mt)
#pragma unroll
            for (int nt = 0; nt < NT; ++nt)
                acc[mt][nt] = __builtin_amdgcn_mfma_f32_16x16x32_bf16(
                    afr[mt], bfr[nt], acc[mt][nt], 0, 0, 0);
    }
#pragma unroll
    for (int mt = 0; mt < MT; ++mt) {
        int grow0 = m0 + wm * MT * 16 + mt * 16 + quad * 4;
#pragma unroll
        for (int nt = 0; nt < NT; ++nt) {
            int gcol = n0 + wn * NT * 16 + nt * 16 + mloc;
#pragma unroll
            for (int r = 0; r < 4; ++r) {
                size_t idx = (size_t)(grow0 + r) * CS + gcol;
                float v = acc[mt][nt][r];
                if (ADD_X && blockIdx.z == 0) v += X[idx];
                unsafeAtomicAdd(&Cout[idx], v);
            }
        }
    }
}

// ---------------- dt GEMM: dt = softplus(xdbl[:, :64] @ Wdt_pad^T + b) -----
__global__ __launch_bounds__(256) void dtgemm_k(
    const float* __restrict__ xdbl, const u16* __restrict__ Wdt,
    const float* __restrict__ bias, u16* __restrict__ dtout)
{
    __shared__ __align__(16) u16 Bs[64 * 72];
    int tid = threadIdx.x, wave = tid >> 6, lane = tid & 63;
    int m0 = blockIdx.x * 64, n0 = blockIdx.y * 64;
    int mloc = lane & 15, quad = lane >> 4;
    {
        int r = tid >> 3, ck = (tid & 7) * 8;
#pragma unroll
        for (int rr = 0; rr < 64; rr += 32) {
            int4 bv = *(const int4*)(Wdt + (size_t)(n0 + r + rr) * 64 + ck);
            *(int4*)(&Bs[(r + rr) * 72 + ck]) = bv;
        }
    }
    int arow = m0 + wave * 16 + mloc;
    const float* ar = xdbl + (size_t)arow * XDS + quad * 8;
    short8 af[2];
#pragma unroll
    for (int h = 0; h < 2; ++h) {
        float4 a0 = *(const float4*)(ar + h * 32);
        float4 a1 = *(const float4*)(ar + h * 32 + 4);
        short8 t;
        t[0]=(short)f2bf(a0.x); t[1]=(short)f2bf(a0.y);
        t[2]=(short)f2bf(a0.z); t[3]=(short)f2bf(a0.w);
        t[4]=(short)f2bf(a1.x); t[5]=(short)f2bf(a1.y);
        t[6]=(short)f2bf(a1.z); t[7]=(short)f2bf(a1.w);
        af[h] = t;
    }
    __syncthreads();
    f32x4 acc[4] = {};
#pragma unroll
    for (int h = 0; h < 2; ++h)
#pragma unroll
        for (int nt = 0; nt < 4; ++nt) {
            short8 bf = *(const short8*)(&Bs[(nt * 16 + mloc) * 72 + h * 32 + quad * 8]);
            acc[nt] = __builtin_amdgcn_mfma_f32_16x16x32_bf16(af[h], bf, acc[nt], 0, 0, 0);
        }
#pragma unroll
    for (int nt = 0; nt < 4; ++nt) {
        int gcol = n0 + nt * 16 + mloc;
        int grow = m0 + wave * 16 + quad * 4;
#pragma unroll
        for (int r = 0; r < 4; ++r) {
            float t = acc[nt][r] + bias[gcol];
            float sp = (t > 15.f) ? t : __logf(1.f + __expf(t));
            dtout[(size_t)(grow + r) * D_INNER + gcol] = f2bf(sp);
        }
    }
}

// ---------------- depthwise causal conv4 + SiLU (4-wide in c) --------------
__global__ __launch_bounds__(256) void conv_silu_k(
    const u16* __restrict__ xz, const float* __restrict__ cw,
    const float* __restrict__ cb, u16* __restrict__ xc)
{
    int gid = blockIdx.x * 256 + threadIdx.x;     // NROW * D_INNER/4
    int r = gid / (D_INNER / 4);
    int c4 = (gid - r * (D_INNER / 4)) * 4;
    int t = r & (SEQ - 1);
    float4 cbv = *(const float4*)(cb + c4);
    float acc[4] = {cbv.x, cbv.y, cbv.z, cbv.w};
    float4 wv[4];
#pragma unroll
    for (int j = 0; j < 4; ++j) wv[j] = *(const float4*)(cw + (c4 + j) * 4);
#pragma unroll
    for (int k = 0; k < 4; ++k) {
        int tt = t - 3 + k;
        if (tt >= 0) {
            ushort4 xv = *(const ushort4*)(xz + (size_t)(r - 3 + k) * D_XZ + c4);
            acc[0] += bf2f(xv.x) * ((const float*)&wv[0])[k];
            acc[1] += bf2f(xv.y) * ((const float*)&wv[1])[k];
            acc[2] += bf2f(xv.z) * ((const float*)&wv[2])[k];
            acc[3] += bf2f(xv.w) * ((const float*)&wv[3])[k];
        }
    }
    ushort4 o;
    o.x = f2bf(acc[0] / (1.f + __expf(-acc[0])));
    o.y = f2bf(acc[1] / (1.f + __expf(-acc[1])));
    o.z = f2bf(acc[2] / (1.f + __expf(-acc[2])));
    o.w = f2bf(acc[3] / (1.f + __expf(-acc[3])));
    *(ushort4*)(xc + (size_t)r * D_INNER + c4) = o;
}

// ======= fused cooperative scan: p1 + p2 + p3 in one kernel ================
// grid = 768 blocks (B*NCHUNK*D_INNER/256 = 2*64*1536/256), 3 blocks/CU.
// Phase1: per-thread local chunk scan (CLEN=16), inputs kept in registers.
// grid.sync. Phase2: blocks 0..191 combine 64 chunks serially per (b,d,n).
// grid.sync. Phase3: re-scan seeded with carry, reusing registers + LDS B/C.
__global__ __launch_bounds__(256, 3) void scan_fused(
    const u16* __restrict__ dt, const u16* __restrict__ xc,
    const u16* __restrict__ xz, const float* __restrict__ xdbl,
    const float* __restrict__ negA, const float* __restrict__ Dp,
    float* __restrict__ Sbuf, float* __restrict__ dtsumbuf,
    float* __restrict__ carry, u16* __restrict__ yy)
{
    __shared__ float BCsh[CLEN][2 * D_STATE];   // 16 rows x (16 B | 16 C)
    cg::grid_group grid = cg::this_grid();
    int tid = threadIdx.x;
    int gid = blockIdx.x * 256 + tid;
    int d = gid % D_INNER;
    int bcN = gid / D_INNER;
    int c = bcN % NCHUNK, b = bcN / NCHUNK;
    size_t r0 = (size_t)b * SEQ + c * CLEN;
    // stage B/C for this chunk's 16 rows: 512 floats, 2 per thread
#pragma unroll
    for (int j = 0; j < 2; ++j) {
        int idx = tid + j * 256;
        int row = idx >> 5, col = idx & 31;
        BCsh[row][col] = xdbl[(r0 + row) * XDS + DT_RANK + col];
    }
    float a[D_STATE];
    {
        const float4* Ar = (const float4*)(negA + d * D_STATE);
        float4 a0 = Ar[0], a1 = Ar[1], a2 = Ar[2], a3 = Ar[3];
        a[0]=a0.x; a[1]=a0.y; a[2]=a0.z; a[3]=a0.w;
        a[4]=a1.x; a[5]=a1.y; a[6]=a1.z; a[7]=a1.w;
        a[8]=a2.x; a[9]=a2.y; a[10]=a2.z; a[11]=a2.w;
        a[12]=a3.x; a[13]=a3.y; a[14]=a3.z; a[15]=a3.w;
    }
    float dtv[CLEN], xcv[CLEN], zv[CLEN];
    {
        const u16* dp = dt + r0 * D_INNER + d;
        const u16* xp = xc + r0 * D_INNER + d;
        const u16* zp = xz + r0 * D_XZ + D_INNER + d;
#pragma unroll
        for (int t = 0; t < CLEN; ++t) {
            dtv[t] = bf2f(dp[t * D_INNER]);
            xcv[t] = bf2f(xp[t * D_INNER]);
            zv[t]  = bf2f(zp[t * D_XZ]);
        }
    }
    float dpv = Dp[d];
    __syncthreads();
    // ---- phase 1: local scan from 0
    {
        float s[D_STATE] = {};
        float dtsum = 0.f;
#pragma unroll
        for (int t = 0; t < CLEN; ++t) {
            dtsum += dtv[t];
            float du = dtv[t] * xcv[t];
#pragma unroll
            for (int n = 0; n < D_STATE; ++n)
                s[n] = __expf(dtv[t] * a[n]) * s[n] + du * BCsh[t][n];
        }
        float4* So = (float4*)(Sbuf + (size_t)gid * D_STATE);
#pragma unroll
        for (int j = 0; j < 4; ++j)
            So[j] = make_float4(s[j*4], s[j*4+1], s[j*4+2], s[j*4+3]);
        dtsumbuf[gid] = dtsum;
    }
    grid.sync();
    // ---- phase 2: 192 blocks combine chunks serially per (b,d,n)
    if (blockIdx.x < (2 * D_INNER * D_STATE) / 256) {
        int g2 = blockIdx.x * 256 + tid;
        int n2 = g2 % D_STATE;
        int d2 = (g2 / D_STATE) % D_INNER;
        int b2 = g2 / (D_STATE * D_INNER);
        float a2 = negA[d2 * D_STATE + n2];
        float s = 0.f;
#pragma unroll 8
        for (int cc = 0; cc < NCHUNK; ++cc) {
            size_t idx = ((size_t)(b2 * NCHUNK + cc) * D_INNER + d2);
            carry[idx * D_STATE + n2] = s;
            s = Sbuf[idx * D_STATE + n2] + __expf(a2 * dtsumbuf[idx]) * s;
        }
    }
    grid.sync();
    // ---- phase 3: seeded re-scan, registers + LDS persist
    {
        float s[D_STATE];
        const float4* Ci = (const float4*)(carry + (size_t)gid * D_STATE);
        float4 c0 = Ci[0], c1 = Ci[1], c2 = Ci[2], c3 = Ci[3];
        s[0]=c0.x; s[1]=c0.y; s[2]=c0.z; s[3]=c0.w;
        s[4]=c1.x; s[5]=c1.y; s[6]=c1.z; s[7]=c1.w;
        s[8]=c2.x; s[9]=c2.y; s[10]=c2.z; s[11]=c2.w;
        s[12]=c3.x; s[13]=c3.y; s[14]=c3.z; s[15]=c3.w;
        u16* yp = yy + r0 * D_INNER + d;
#pragma unroll
        for (int t = 0; t < CLEN; ++t) {
            float du = dtv[t] * xcv[t];
            float y = 0.f;
#pragma unroll
            for (int n = 0; n < D_STATE; ++n) {
                s[n] = __expf(dtv[t] * a[n]) * s[n] + du * BCsh[t][n];
                y += s[n] * BCsh[t][D_STATE + n];
            }
            float yv = y + dpv * xcv[t];
            float sig = 1.f / (1.f + __expf(-zv[t]));
            yp[t * D_INNER] = f2bf(yv * (zv[t] * sig));
        }
    }
}

extern "C" void kernel_launch(void* const* d_in, const int* in_sizes, int n_in,
                              void* d_out, int out_size, void* d_ws, size_t ws_size,
                              hipStream_t stream) {
    const float* x      = (const float*)d_in[0];
    const float* ln_g   = (const float*)d_in[1];
    const float* ln_b   = (const float*)d_in[2];
    const float* W_in   = (const float*)d_in[3];
    const float* conv_w = (const float*)d_in[4];
    const float* conv_b = (const float*)d_in[5];
    const float* W_xp   = (const float*)d_in[6];
    const float* W_dt   = (const float*)d_in[7];
    const float* b_dt   = (const float*)d_in[8];
    const float* A_log  = (const float*)d_in[9];
    const float* Dp     = (const float*)d_in[10];
    const float* W_out  = (const float*)d_in[11];
    float* out = (float*)d_out;

    char* ws = (char*)d_ws;
    u16*   h_bf    = (u16*)ws;   ws += (size_t)NROW * D_MODEL * 2;
    u16*   xz_bf   = (u16*)ws;   ws += (size_t)NROW * D_XZ * 2;
    u16*   xc_bf   = (u16*)ws;   ws += (size_t)NROW * D_INNER * 2;
    float* xdbl    = (float*)ws; ws += (size_t)NROW * XDS * 4;
    u16*   dtbuf   = (u16*)ws;   ws += (size_t)NROW * D_INNER * 2;
    u16*   yybuf   = (u16*)ws;   ws += (size_t)NROW * D_INNER * 2;
    u16*   Win_bf  = (u16*)ws;   ws += (size_t)D_XZ * D_MODEL * 2;
    u16*   Wout_bf = (u16*)ws;   ws += (size_t)D_MODEL * D_INNER * 2;
    u16*   Wxp_bf  = (u16*)ws;   ws += (size_t)XDS * D_INNER * 2;
    u16*   Wdt_bf  = (u16*)ws;   ws += (size_t)D_INNER * 64 * 2;
    float* negA    = (float*)ws; ws += (size_t)D_INNER * D_STATE * 4;
    float* Sbuf    = (float*)ws; ws += (size_t)2 * NCHUNK * D_INNER * 16 * 4;
    float* dtsumb  = (float*)ws; ws += (size_t)2 * NCHUNK * D_INNER * 4;
    float* carryb  = (float*)ws;

    // prep: LN rows (2048 blocks) + weight-convert/zeroing (5560 blocks)
    prep_ln_k<<<NROW + PREP_BLOCKS, 256, 0, stream>>>(
        x, ln_g, ln_b, h_bf, W_in, W_out, W_xp, W_dt, A_log,
        Win_bf, Wout_bf, Wxp_bf, Wdt_bf, negA, xdbl, out);

    // GEMM1: 2048x3072x768, 128x64 tiles -> 768 blocks (3/CU)
    gemm128<4, 2, true><<<dim3(NROW / 128, D_XZ / 64), 256, 0, stream>>>(
        h_bf, Win_bf, xz_bf, NROW, D_XZ, D_MODEL);
    conv_silu_k<<<NROW * (D_INNER / 4) / 256, 256, 0, stream>>>(
        xz_bf, conv_w, conv_b, xc_bf);
    // xproj: 64x128 tile, split-K x8 (slice 192) -> 256 blocks
    gemm_splitk<2, 4, 192, false><<<dim3(NROW / 64, 1, 8), 256, 0, stream>>>(
        xc_bf, Wxp_bf, nullptr, xdbl, D_INNER, XDS);
    // dt: 2048x1536x64, bf16 out; 768 blocks
    dtgemm_k<<<dim3(NROW / 64, D_INNER / 64), 256, 0, stream>>>(
        xdbl, Wdt_bf, b_dt, dtbuf);

    // fused scan: 768 cooperative blocks, 2 grid syncs
    {
        void* args[] = {
            (void*)&dtbuf, (void*)&xc_bf, (void*)&xz_bf, (void*)&xdbl,
            (void*)&negA, (void*)&Dp, (void*)&Sbuf, (void*)&dtsumb,
            (void*)&carryb, (void*)&yybuf
        };
        hipLaunchCooperativeKernel((void*)scan_fused,
                                   dim3(2 * NCHUNK * D_INNER / 256), dim3(256),
                                   args, 0, stream);
    }

    // GEMM-out: 2048x768x1536, 64x64 tiles, split-K x2 -> 768 blocks; +x via kz==0
    gemm_splitk<2, 2, 768, true><<<dim3(NROW / 64, D_MODEL / 64, 2), 256, 0, stream>>>(
        yybuf, Wout_bf, x, out, D_INNER, D_MODEL);
}

// Round 9
// 203.736 us; speedup vs baseline: 2.5184x; 2.5184x over previous
//
#include <hip/hip_runtime.h>

typedef unsigned short u16;
typedef unsigned int u32;
typedef __attribute__((ext_vector_type(8))) short short8;
typedef __attribute__((ext_vector_type(4))) float f32x4;

#define D_MODEL 768
#define D_INNER 1536
#define D_XZ    3072
#define D_STATE 16
#define DT_RANK 48
#define NROW    2048   // B*T
#define SEQ     1024
#define XDS     128    // padded x_dbl row stride (48 dt_r | 16 B | 16 C | pad)
#define NCHUNK  128
#define CLEN    8      // SEQ / NCHUNK

typedef const __attribute__((address_space(1))) u32 glb_u32;
typedef __attribute__((address_space(3))) u32 lds_u32;

__device__ __forceinline__ float bf2f(u16 u) {
    union { unsigned int i; float f; } v; v.i = ((unsigned int)u) << 16; return v.f;
}
__device__ __forceinline__ u16 f2bf(float f) {
    union { float f; unsigned int i; } v; v.f = f;
    unsigned int r = v.i + 0x7fffu + ((v.i >> 16) & 1u);
    return (u16)(r >> 16);
}
__device__ __forceinline__ void g2lds16(const u16* g, u16* l) {
    __builtin_amdgcn_global_load_lds((glb_u32*)g, (lds_u32*)l, 16, 0, 0);
}

// ======== fused prep: LayerNorm (blocks 0..2047) + weight prep/zeroing =====
// NOTE: no cooperative anything — grid.sync() on MI355X flushes per-XCD L2
// (measured r8: 345 MB HBM traffic, 315 µs). Separate kernels are cheaper.
#define N0 (D_XZ * D_MODEL / 4)        // 589824  Win->bf16
#define N1 (D_MODEL * D_INNER / 4)     // 294912  Wout->bf16
#define N2 (XDS * D_INNER / 4)         // 49152   Wxp pad128->bf16
#define N3 (D_INNER * 64 / 4)          // 24576   Wdt pad64->bf16
#define N4 (D_INNER * D_STATE / 4)     // 6144    negA
#define N5 (NROW * XDS / 4)            // 65536   zero xdbl
#define PREP_BLOCKS ((N0+N1+N2+N3+N4+N5) / 256)   // 4024
__global__ __launch_bounds__(256) void prep_ln_k(
    const float* __restrict__ x, const float* __restrict__ g,
    const float* __restrict__ bln, u16* __restrict__ h,
    const float* __restrict__ W_in, const float* __restrict__ W_out,
    const float* __restrict__ W_xp, const float* __restrict__ W_dt,
    const float* __restrict__ A_log,
    u16* __restrict__ Win_bf, u16* __restrict__ Wout_bf,
    u16* __restrict__ Wxp_bf, u16* __restrict__ Wdt_bf,
    float* __restrict__ negA, float* __restrict__ xdbl)
{
    __shared__ float sred[4], sqred[4];
    int tid = threadIdx.x;
    if (blockIdx.x < NROW) {
        int row = blockIdx.x;
        const float* xr = x + (size_t)row * D_MODEL;
        float v[3], s = 0.f, sq = 0.f;
#pragma unroll
        for (int j = 0; j < 3; ++j) {
            v[j] = xr[tid + j * 256];
            s += v[j]; sq += v[j] * v[j];
        }
#pragma unroll
        for (int off = 32; off >= 1; off >>= 1) {
            s  += __shfl_xor(s,  off, 64);
            sq += __shfl_xor(sq, off, 64);
        }
        if ((tid & 63) == 0) { sred[tid >> 6] = s; sqred[tid >> 6] = sq; }
        __syncthreads();
        float st = sred[0] + sred[1] + sred[2] + sred[3];
        float sqt = sqred[0] + sqred[1] + sqred[2] + sqred[3];
        float mu = st * (1.f / D_MODEL);
        float var = sqt * (1.f / D_MODEL) - mu * mu;
        float rstd = rsqrtf(var + 1e-5f);
        u16* hr = h + (size_t)row * D_MODEL;
#pragma unroll
        for (int j = 0; j < 3; ++j) {
            int idx = tid + j * 256;
            hr[idx] = f2bf((v[j] - mu) * rstd * g[idx] + bln[idx]);
        }
        return;
    }
    int gid = (blockIdx.x - NROW) * 256 + tid;
    if (gid < N0) {
        float4 v = *(const float4*)(W_in + (size_t)gid * 4);
        u16* o = Win_bf + (size_t)gid * 4;
        o[0]=f2bf(v.x); o[1]=f2bf(v.y); o[2]=f2bf(v.z); o[3]=f2bf(v.w);
    } else if (gid < N0 + N1) {
        int i = gid - N0;
        float4 v = *(const float4*)(W_out + (size_t)i * 4);
        u16* o = Wout_bf + (size_t)i * 4;
        o[0]=f2bf(v.x); o[1]=f2bf(v.y); o[2]=f2bf(v.z); o[3]=f2bf(v.w);
    } else if (gid < N0 + N1 + N2) {
        int i = gid - N0 - N1;
        int n = (i * 4) / D_INNER, k = (i * 4) % D_INNER;
        u16* o = Wxp_bf + (size_t)i * 4;
        if (n < 80) {
            float4 v = *(const float4*)(W_xp + (size_t)n * D_INNER + k);
            o[0]=f2bf(v.x); o[1]=f2bf(v.y); o[2]=f2bf(v.z); o[3]=f2bf(v.w);
        } else { o[0]=0; o[1]=0; o[2]=0; o[3]=0; }
    } else if (gid < N0 + N1 + N2 + N3) {
        int i = gid - N0 - N1 - N2;
        int r = (i * 4) >> 6, c0 = (i * 4) & 63;
        u16* o = Wdt_bf + (size_t)i * 4;
        if (c0 < DT_RANK) {
            float4 v = *(const float4*)(W_dt + (size_t)r * DT_RANK + c0);
            o[0]=f2bf(v.x); o[1]=f2bf(v.y); o[2]=f2bf(v.z); o[3]=f2bf(v.w);
        } else { o[0]=0; o[1]=0; o[2]=0; o[3]=0; }
    } else if (gid < N0 + N1 + N2 + N3 + N4) {
        int i = gid - N0 - N1 - N2 - N3;
        float4 v = *(const float4*)(A_log + (size_t)i * 4);
        *(float4*)(negA + (size_t)i * 4) =
            make_float4(-__expf(v.x), -__expf(v.y), -__expf(v.z), -__expf(v.w));
    } else if (gid < N0 + N1 + N2 + N3 + N4 + N5) {
        int i = gid - N0 - N1 - N2 - N3 - N4;
        *(float4*)(xdbl + (size_t)i * 4) = make_float4(0.f, 0.f, 0.f, 0.f);
    }
}

// ============ m97-style MFMA GEMM: C(MxN) = A(MxK) * B(NxK)^T ==============
// ADD_RES: add f32 residual Res before store.
template<int MT, int NT, bool OUT_BF16, bool ADD_RES>
__global__ __launch_bounds__(256) void gemm128(
    const u16* __restrict__ A, const u16* __restrict__ B,
    const float* __restrict__ Res, void* __restrict__ Cv,
    int M, int N, int K)
{
    constexpr int BM = 32 * MT, BN = 32 * NT;
    __shared__ __align__(16) u16 As[BM * 32];
    __shared__ __align__(16) u16 Bs[BN * 32];
    int tid = threadIdx.x, w = tid >> 6, lane = tid & 63;
    int wm = w & 1, wn = w >> 1;
    int m0 = blockIdx.x * BM, n0 = blockIdx.y * BN;
    int mloc = lane & 15, quad = lane >> 4;
    int lr = lane >> 2, lc = lane & 3;
    f32x4 acc[MT][NT] = {};

    for (int k0 = 0; k0 < K; k0 += 32) {
        __syncthreads();
#pragma unroll
        for (int j = w; j < 2 * MT; j += 4) {
            int row = j * 16 + lr;
            int cb = lc ^ ((row >> 1) & 3);
            g2lds16(A + (size_t)(m0 + row) * K + k0 + cb * 8, &As[j * 512]);
        }
#pragma unroll
        for (int j = w; j < 2 * NT; j += 4) {
            int row = j * 16 + lr;
            int cb = lc ^ ((row >> 1) & 3);
            g2lds16(B + (size_t)(n0 + row) * K + k0 + cb * 8, &Bs[j * 512]);
        }
        __syncthreads();
        short8 afr[MT], bfr[NT];
#pragma unroll
        for (int mt = 0; mt < MT; ++mt) {
            int row = wm * MT * 16 + mt * 16 + mloc;
            int cb = quad ^ ((row >> 1) & 3);
            afr[mt] = *(const short8*)(&As[row * 32 + cb * 8]);
        }
#pragma unroll
        for (int nt = 0; nt < NT; ++nt) {
            int row = wn * NT * 16 + nt * 16 + mloc;
            int cb = quad ^ ((row >> 1) & 3);
            bfr[nt] = *(const short8*)(&Bs[row * 32 + cb * 8]);
        }
#pragma unroll
        for (int mt = 0; mt < MT; ++mt)
#pragma unroll
            for (int nt = 0; nt < NT; ++nt)
                acc[mt][nt] = __builtin_amdgcn_mfma_f32_16x16x32_bf16(
                    afr[mt], bfr[nt], acc[mt][nt], 0, 0, 0);
    }
    // C/D layout: col = lane&15, row = quad*4 + reg  [verified m89/m91]
#pragma unroll
    for (int mt = 0; mt < MT; ++mt) {
        int grow0 = m0 + wm * MT * 16 + mt * 16 + quad * 4;
#pragma unroll
        for (int nt = 0; nt < NT; ++nt) {
            int gcol = n0 + wn * NT * 16 + nt * 16 + mloc;
#pragma unroll
            for (int r = 0; r < 4; ++r) {
                size_t idx = (size_t)(grow0 + r) * N + gcol;
                float v = acc[mt][nt][r];
                if (ADD_RES) v += Res[idx];
                if (OUT_BF16) ((u16*)Cv)[idx] = f2bf(v);
                else          ((float*)Cv)[idx] = v;
            }
        }
    }
}

// ---------- split-K MFMA GEMM, f32 atomic-add epilogue (xproj only) --------
template<int MT, int NT, int KSLICE>
__global__ __launch_bounds__(256) void gemm_splitk(
    const u16* __restrict__ A, const u16* __restrict__ B,
    float* __restrict__ Cout, int K, int CS)
{
    constexpr int BM = 32 * MT, BN = 32 * NT;
    __shared__ __align__(16) u16 As[BM * 32];
    __shared__ __align__(16) u16 Bs[BN * 32];
    int tid = threadIdx.x, w = tid >> 6, lane = tid & 63;
    int wm = w & 1, wn = w >> 1;
    int m0 = blockIdx.x * BM, n0 = blockIdx.y * BN;
    int kbase = blockIdx.z * KSLICE;
    int mloc = lane & 15, quad = lane >> 4;
    int lr = lane >> 2, lc = lane & 3;
    f32x4 acc[MT][NT] = {};

    for (int k0 = 0; k0 < KSLICE; k0 += 32) {
        __syncthreads();
#pragma unroll
        for (int j = w; j < 2 * MT; j += 4) {
            int row = j * 16 + lr;
            int cb = lc ^ ((row >> 1) & 3);
            g2lds16(A + (size_t)(m0 + row) * K + kbase + k0 + cb * 8, &As[j * 512]);
        }
#pragma unroll
        for (int j = w; j < 2 * NT; j += 4) {
            int row = j * 16 + lr;
            int cb = lc ^ ((row >> 1) & 3);
            g2lds16(B + (size_t)(n0 + row) * K + kbase + k0 + cb * 8, &Bs[j * 512]);
        }
        __syncthreads();
        short8 afr[MT], bfr[NT];
#pragma unroll
        for (int mt = 0; mt < MT; ++mt) {
            int row = wm * MT * 16 + mt * 16 + mloc;
            int cb = quad ^ ((row >> 1) & 3);
            afr[mt] = *(const short8*)(&As[row * 32 + cb * 8]);
        }
#pragma unroll
        for (int nt = 0; nt < NT; ++nt) {
            int row = wn * NT * 16 + nt * 16 + mloc;
            int cb = quad ^ ((row >> 1) & 3);
            bfr[nt] = *(const short8*)(&Bs[row * 32 + cb * 8]);
        }
#pragma unroll
        for (int mt = 0; mt < MT; ++mt)
#pragma unroll
            for (int nt = 0; nt < NT; ++nt)
                acc[mt][nt] = __builtin_amdgcn_mfma_f32_16x16x32_bf16(
                    afr[mt], bfr[nt], acc[mt][nt], 0, 0, 0);
    }
#pragma unroll
    for (int mt = 0; mt < MT; ++mt) {
        int grow0 = m0 + wm * MT * 16 + mt * 16 + quad * 4;
#pragma unroll
        for (int nt = 0; nt < NT; ++nt) {
            int gcol = n0 + wn * NT * 16 + nt * 16 + mloc;
#pragma unroll
            for (int r = 0; r < 4; ++r)
                unsafeAtomicAdd(&Cout[(size_t)(grow0 + r) * CS + gcol],
                                acc[mt][nt][r]);
        }
    }
}

// ---------------- dt GEMM: dt = softplus(xdbl[:, :64] @ Wdt_pad^T + b) -----
__global__ __launch_bounds__(256) void dtgemm_k(
    const float* __restrict__ xdbl, const u16* __restrict__ Wdt,
    const float* __restrict__ bias, u16* __restrict__ dtout)
{
    __shared__ __align__(16) u16 Bs[64 * 72];
    int tid = threadIdx.x, wave = tid >> 6, lane = tid & 63;
    int m0 = blockIdx.x * 64, n0 = blockIdx.y * 64;
    int mloc = lane & 15, quad = lane >> 4;
    {
        int r = tid >> 3, ck = (tid & 7) * 8;
#pragma unroll
        for (int rr = 0; rr < 64; rr += 32) {
            int4 bv = *(const int4*)(Wdt + (size_t)(n0 + r + rr) * 64 + ck);
            *(int4*)(&Bs[(r + rr) * 72 + ck]) = bv;
        }
    }
    int arow = m0 + wave * 16 + mloc;
    const float* ar = xdbl + (size_t)arow * XDS + quad * 8;
    short8 af[2];
#pragma unroll
    for (int h = 0; h < 2; ++h) {
        float4 a0 = *(const float4*)(ar + h * 32);
        float4 a1 = *(const float4*)(ar + h * 32 + 4);
        short8 t;
        t[0]=(short)f2bf(a0.x); t[1]=(short)f2bf(a0.y);
        t[2]=(short)f2bf(a0.z); t[3]=(short)f2bf(a0.w);
        t[4]=(short)f2bf(a1.x); t[5]=(short)f2bf(a1.y);
        t[6]=(short)f2bf(a1.z); t[7]=(short)f2bf(a1.w);
        af[h] = t;
    }
    __syncthreads();
    f32x4 acc[4] = {};
#pragma unroll
    for (int h = 0; h < 2; ++h)
#pragma unroll
        for (int nt = 0; nt < 4; ++nt) {
            short8 bf = *(const short8*)(&Bs[(nt * 16 + mloc) * 72 + h * 32 + quad * 8]);
            acc[nt] = __builtin_amdgcn_mfma_f32_16x16x32_bf16(af[h], bf, acc[nt], 0, 0, 0);
        }
#pragma unroll
    for (int nt = 0; nt < 4; ++nt) {
        int gcol = n0 + nt * 16 + mloc;
        int grow = m0 + wave * 16 + quad * 4;
#pragma unroll
        for (int r = 0; r < 4; ++r) {
            float t = acc[nt][r] + bias[gcol];
            float sp = (t > 15.f) ? t : __logf(1.f + __expf(t));
            dtout[(size_t)(grow + r) * D_INNER + gcol] = f2bf(sp);
        }
    }
}

// ---------------- depthwise causal conv4 + SiLU (4-wide in c) --------------
__global__ __launch_bounds__(256) void conv_silu_k(
    const u16* __restrict__ xz, const float* __restrict__ cw,
    const float* __restrict__ cb, u16* __restrict__ xc)
{
    int gid = blockIdx.x * 256 + threadIdx.x;     // NROW * D_INNER/4
    int r = gid / (D_INNER / 4);
    int c4 = (gid - r * (D_INNER / 4)) * 4;
    int t = r & (SEQ - 1);
    float4 cbv = *(const float4*)(cb + c4);
    float acc[4] = {cbv.x, cbv.y, cbv.z, cbv.w};
    float4 wv[4];
#pragma unroll
    for (int j = 0; j < 4; ++j) wv[j] = *(const float4*)(cw + (c4 + j) * 4);
#pragma unroll
    for (int k = 0; k < 4; ++k) {
        int tt = t - 3 + k;
        if (tt >= 0) {
            ushort4 xv = *(const ushort4*)(xz + (size_t)(r - 3 + k) * D_XZ + c4);
            acc[0] += bf2f(xv.x) * ((const float*)&wv[0])[k];
            acc[1] += bf2f(xv.y) * ((const float*)&wv[1])[k];
            acc[2] += bf2f(xv.z) * ((const float*)&wv[2])[k];
            acc[3] += bf2f(xv.w) * ((const float*)&wv[3])[k];
        }
    }
    ushort4 o;
    o.x = f2bf(acc[0] / (1.f + __expf(-acc[0])));
    o.y = f2bf(acc[1] / (1.f + __expf(-acc[1])));
    o.z = f2bf(acc[2] / (1.f + __expf(-acc[2])));
    o.w = f2bf(acc[3] / (1.f + __expf(-acc[3])));
    *(ushort4*)(xc + (size_t)r * D_INNER + c4) = o;
}

// ================= chunked parallel scan (CLEN=8, LDS-staged B/C) ==========
__global__ __launch_bounds__(256) void scan_p1(
    const u16* __restrict__ dt, const u16* __restrict__ xc,
    const float* __restrict__ xdbl, const float* __restrict__ negA,
    float* __restrict__ Sbuf, float* __restrict__ dtsumbuf)
{
    __shared__ float Bsh[CLEN][D_STATE];
    int tid = threadIdx.x;
    int gid = blockIdx.x * 256 + tid;
    int d = gid % D_INNER;
    int bcN = gid / D_INNER;
    int c = bcN % NCHUNK, b = bcN / NCHUNK;
    size_t r0 = (size_t)b * SEQ + c * CLEN;
    if (tid < CLEN * D_STATE) {
        int tt = tid >> 4, n = tid & 15;
        Bsh[tt][n] = xdbl[(r0 + tt) * XDS + DT_RANK + n];
    }
    float a[D_STATE], s[D_STATE] = {};
    {
        const float4* Ar = (const float4*)(negA + d * D_STATE);
        float4 a0 = Ar[0], a1 = Ar[1], a2 = Ar[2], a3 = Ar[3];
        a[0]=a0.x; a[1]=a0.y; a[2]=a0.z; a[3]=a0.w;
        a[4]=a1.x; a[5]=a1.y; a[6]=a1.z; a[7]=a1.w;
        a[8]=a2.x; a[9]=a2.y; a[10]=a2.z; a[11]=a2.w;
        a[12]=a3.x; a[13]=a3.y; a[14]=a3.z; a[15]=a3.w;
    }
    float dtv[CLEN], du[CLEN];
    const u16* dp = dt + r0 * D_INNER + d;
    const u16* xp = xc + r0 * D_INNER + d;
#pragma unroll
    for (int t = 0; t < CLEN; ++t) {
        dtv[t] = bf2f(dp[t * D_INNER]);
        du[t] = dtv[t] * bf2f(xp[t * D_INNER]);
    }
    __syncthreads();
    float dtsum = 0.f;
#pragma unroll
    for (int t = 0; t < CLEN; ++t) {
        dtsum += dtv[t];
#pragma unroll
        for (int n = 0; n < D_STATE; ++n)
            s[n] = __expf(dtv[t] * a[n]) * s[n] + du[t] * Bsh[t][n];
    }
    float4* So = (float4*)(Sbuf + (size_t)gid * D_STATE);
#pragma unroll
    for (int j = 0; j < 4; ++j)
        So[j] = make_float4(s[j*4], s[j*4+1], s[j*4+2], s[j*4+3]);
    dtsumbuf[gid] = dtsum;
}

__global__ __launch_bounds__(256) void scan_p2(
    const float* __restrict__ Sbuf, const float* __restrict__ dtsumbuf,
    const float* __restrict__ negA, float* __restrict__ carry)
{
    int gid = blockIdx.x * 256 + threadIdx.x;   // B*D_INNER*16
    int n = gid % D_STATE;
    int d = (gid / D_STATE) % D_INNER;
    int b = gid / (D_STATE * D_INNER);
    float a = negA[d * D_STATE + n];
    float s = 0.f;
#pragma unroll 8
    for (int c = 0; c < NCHUNK; ++c) {
        size_t idx = ((size_t)(b * NCHUNK + c) * D_INNER + d);
        carry[idx * D_STATE + n] = s;
        s = Sbuf[idx * D_STATE + n] + __expf(a * dtsumbuf[idx]) * s;
    }
}

__global__ __launch_bounds__(256) void scan_p3(
    const u16* __restrict__ dt, const u16* __restrict__ xc,
    const u16* __restrict__ xz, const float* __restrict__ xdbl,
    const float* __restrict__ negA, const float* __restrict__ Dp,
    const float* __restrict__ carry, u16* __restrict__ yy)
{
    __shared__ float BCsh[CLEN][2 * D_STATE];
    int tid = threadIdx.x;
    int gid = blockIdx.x * 256 + tid;
    int d = gid % D_INNER;
    int bcN = gid / D_INNER;
    int c = bcN % NCHUNK, b = bcN / NCHUNK;
    size_t r0 = (size_t)b * SEQ + c * CLEN;
    {
        int tt = tid >> 5, j = tid & 31;   // 256 = 8 rows x 32 vals
        BCsh[tt][j] = xdbl[(r0 + tt) * XDS + DT_RANK + j];
    }
    float a[D_STATE], s[D_STATE];
    {
        const float4* Ci = (const float4*)(carry + (size_t)gid * D_STATE);
        float4 c0 = Ci[0], c1 = Ci[1], c2 = Ci[2], c3 = Ci[3];
        s[0]=c0.x; s[1]=c0.y; s[2]=c0.z; s[3]=c0.w;
        s[4]=c1.x; s[5]=c1.y; s[6]=c1.z; s[7]=c1.w;
        s[8]=c2.x; s[9]=c2.y; s[10]=c2.z; s[11]=c2.w;
        s[12]=c3.x; s[13]=c3.y; s[14]=c3.z; s[15]=c3.w;
        const float4* Ar = (const float4*)(negA + d * D_STATE);
        float4 a0 = Ar[0], a1 = Ar[1], a2 = Ar[2], a3 = Ar[3];
        a[0]=a0.x; a[1]=a0.y; a[2]=a0.z; a[3]=a0.w;
        a[4]=a1.x; a[5]=a1.y; a[6]=a1.z; a[7]=a1.w;
        a[8]=a2.x; a[9]=a2.y; a[10]=a2.z; a[11]=a2.w;
        a[12]=a3.x; a[13]=a3.y; a[14]=a3.z; a[15]=a3.w;
    }
    float dtv[CLEN], xcv[CLEN], zv[CLEN];
    const u16* dp = dt + r0 * D_INNER + d;
    const u16* xp = xc + r0 * D_INNER + d;
    const u16* zp = xz + r0 * D_XZ + D_INNER + d;
#pragma unroll
    for (int t = 0; t < CLEN; ++t) {
        dtv[t] = bf2f(dp[t * D_INNER]);
        xcv[t] = bf2f(xp[t * D_INNER]);
        zv[t]  = bf2f(zp[t * D_XZ]);
    }
    float dpv = Dp[d];
    __syncthreads();
    u16* yp = yy + r0 * D_INNER + d;
#pragma unroll
    for (int t = 0; t < CLEN; ++t) {
        float du = dtv[t] * xcv[t];
        float y = 0.f;
#pragma unroll
        for (int n = 0; n < D_STATE; ++n) {
            s[n] = __expf(dtv[t] * a[n]) * s[n] + du * BCsh[t][n];
            y += s[n] * BCsh[t][D_STATE + n];
        }
        float yv = y + dpv * xcv[t];
        float sig = 1.f / (1.f + __expf(-zv[t]));
        yp[t * D_INNER] = f2bf(yv * (zv[t] * sig));
    }
}

extern "C" void kernel_launch(void* const* d_in, const int* in_sizes, int n_in,
                              void* d_out, int out_size, void* d_ws, size_t ws_size,
                              hipStream_t stream) {
    const float* x      = (const float*)d_in[0];
    const float* ln_g   = (const float*)d_in[1];
    const float* ln_b   = (const float*)d_in[2];
    const float* W_in   = (const float*)d_in[3];
    const float* conv_w = (const float*)d_in[4];
    const float* conv_b = (const float*)d_in[5];
    const float* W_xp   = (const float*)d_in[6];
    const float* W_dt   = (const float*)d_in[7];
    const float* b_dt   = (const float*)d_in[8];
    const float* A_log  = (const float*)d_in[9];
    const float* Dp     = (const float*)d_in[10];
    const float* W_out  = (const float*)d_in[11];
    float* out = (float*)d_out;

    char* ws = (char*)d_ws;
    u16*   h_bf    = (u16*)ws;   ws += (size_t)NROW * D_MODEL * 2;
    u16*   xz_bf   = (u16*)ws;   ws += (size_t)NROW * D_XZ * 2;
    u16*   xc_bf   = (u16*)ws;   ws += (size_t)NROW * D_INNER * 2;
    float* xdbl    = (float*)ws; ws += (size_t)NROW * XDS * 4;
    u16*   dtbuf   = (u16*)ws;   ws += (size_t)NROW * D_INNER * 2;
    u16*   yybuf   = (u16*)ws;   ws += (size_t)NROW * D_INNER * 2;
    u16*   Win_bf  = (u16*)ws;   ws += (size_t)D_XZ * D_MODEL * 2;
    u16*   Wout_bf = (u16*)ws;   ws += (size_t)D_MODEL * D_INNER * 2;
    u16*   Wxp_bf  = (u16*)ws;   ws += (size_t)XDS * D_INNER * 2;
    u16*   Wdt_bf  = (u16*)ws;   ws += (size_t)D_INNER * 64 * 2;
    float* negA    = (float*)ws; ws += (size_t)D_INNER * D_STATE * 4;
    float* Sbuf    = (float*)ws; ws += (size_t)2 * NCHUNK * D_INNER * 16 * 4;
    float* dtsumb  = (float*)ws; ws += (size_t)2 * NCHUNK * D_INNER * 4;
    float* carryb  = (float*)ws;

    // prep: LN rows (2048 blocks) + weight-convert/zeroing (4024 blocks)
    prep_ln_k<<<NROW + PREP_BLOCKS, 256, 0, stream>>>(
        x, ln_g, ln_b, h_bf, W_in, W_out, W_xp, W_dt, A_log,
        Win_bf, Wout_bf, Wxp_bf, Wdt_bf, negA, xdbl);

    // GEMM1: 2048x3072x768, 128x64 tiles -> 768 blocks (3/CU)
    gemm128<4, 2, true, false><<<dim3(NROW / 128, D_XZ / 64), 256, 0, stream>>>(
        h_bf, Win_bf, nullptr, xz_bf, NROW, D_XZ, D_MODEL);
    conv_silu_k<<<NROW * (D_INNER / 4) / 256, 256, 0, stream>>>(
        xz_bf, conv_w, conv_b, xc_bf);
    // xproj: 64x128 tile, split-K x8 (slice 192) -> 256 blocks
    gemm_splitk<2, 4, 192><<<dim3(NROW / 64, 1, 8), 256, 0, stream>>>(
        xc_bf, Wxp_bf, xdbl, D_INNER, XDS);
    // dt: 2048x1536x64, bf16 out; 768 blocks
    dtgemm_k<<<dim3(NROW / 64, D_INNER / 64), 256, 0, stream>>>(
        xdbl, Wdt_bf, b_dt, dtbuf);

    scan_p1<<<2 * NCHUNK * D_INNER / 256, 256, 0, stream>>>(
        dtbuf, xc_bf, xdbl, negA, Sbuf, dtsumb);
    scan_p2<<<2 * D_INNER * D_STATE / 256, 256, 0, stream>>>(
        Sbuf, dtsumb, negA, carryb);
    scan_p3<<<2 * NCHUNK * D_INNER / 256, 256, 0, stream>>>(
        dtbuf, xc_bf, xz_bf, xdbl, negA, Dp, carryb, yybuf);

    // GEMM-out: 2048x768x1536, 64x64 tiles -> 384 blocks, fused +x residual
    gemm128<2, 2, false, true><<<dim3(NROW / 64, D_MODEL / 64), 256, 0, stream>>>(
        yybuf, Wout_bf, x, out, NROW, D_MODEL, D_INNER);
}

// Round 10
// 194.703 us; speedup vs baseline: 2.6352x; 1.0464x over previous
//
#include <hip/hip_runtime.h>

typedef unsigned short u16;
typedef unsigned int u32;
typedef __attribute__((ext_vector_type(8))) short short8;
typedef __attribute__((ext_vector_type(8))) unsigned short ushort8;
typedef __attribute__((ext_vector_type(4))) float f32x4;

#define D_MODEL 768
#define D_INNER 1536
#define D_XZ    3072
#define D_STATE 16
#define DT_RANK 48
#define NROW    2048   // B*T
#define SEQ     1024
#define XDS     128    // padded x_dbl row stride (48 dt_r | 16 B | 16 C | pad)
#define NCHUNK  64
#define CLEN    16     // SEQ / NCHUNK; 768 blocks = 3/CU (don't go below 2/CU: r5)

typedef const __attribute__((address_space(1))) u32 glb_u32;
typedef __attribute__((address_space(3))) u32 lds_u32;

__device__ __forceinline__ float bf2f(u16 u) {
    union { unsigned int i; float f; } v; v.i = ((unsigned int)u) << 16; return v.f;
}
__device__ __forceinline__ u16 f2bf(float f) {
    union { float f; unsigned int i; } v; v.f = f;
    unsigned int r = v.i + 0x7fffu + ((v.i >> 16) & 1u);
    return (u16)(r >> 16);
}
__device__ __forceinline__ void g2lds16(const u16* g, u16* l) {
    __builtin_amdgcn_global_load_lds((glb_u32*)g, (lds_u32*)l, 16, 0, 0);
}

// ======== fused prep: LayerNorm (blocks 0..2047) + weight prep/zeroing =====
// NOTE: no cooperative anything — grid.sync() on MI355X flushes per-XCD L2
// (measured r8: 345 MB HBM traffic, 315 µs). Separate kernels are cheaper.
#define N0 (D_XZ * D_MODEL / 4)        // 589824  Win->bf16
#define N1 (D_MODEL * D_INNER / 4)     // 294912  Wout->bf16
#define N2 (XDS * D_INNER / 4)         // 49152   Wxp pad128->bf16
#define N3 (D_INNER * 64 / 4)          // 24576   Wdt pad64->bf16
#define N4 (D_INNER * D_STATE / 4)     // 6144    negA
#define N5 (NROW * XDS / 4)            // 65536   zero xdbl
#define PREP_BLOCKS ((N0+N1+N2+N3+N4+N5) / 256)   // 4024
__global__ __launch_bounds__(256) void prep_ln_k(
    const float* __restrict__ x, const float* __restrict__ g,
    const float* __restrict__ bln, u16* __restrict__ h,
    const float* __restrict__ W_in, const float* __restrict__ W_out,
    const float* __restrict__ W_xp, const float* __restrict__ W_dt,
    const float* __restrict__ A_log,
    u16* __restrict__ Win_bf, u16* __restrict__ Wout_bf,
    u16* __restrict__ Wxp_bf, u16* __restrict__ Wdt_bf,
    float* __restrict__ negA, float* __restrict__ xdbl)
{
    __shared__ float sred[4], sqred[4];
    int tid = threadIdx.x;
    if (blockIdx.x < NROW) {
        int row = blockIdx.x;
        const float* xr = x + (size_t)row * D_MODEL;
        float v[3], s = 0.f, sq = 0.f;
#pragma unroll
        for (int j = 0; j < 3; ++j) {
            v[j] = xr[tid + j * 256];
            s += v[j]; sq += v[j] * v[j];
        }
#pragma unroll
        for (int off = 32; off >= 1; off >>= 1) {
            s  += __shfl_xor(s,  off, 64);
            sq += __shfl_xor(sq, off, 64);
        }
        if ((tid & 63) == 0) { sred[tid >> 6] = s; sqred[tid >> 6] = sq; }
        __syncthreads();
        float st = sred[0] + sred[1] + sred[2] + sred[3];
        float sqt = sqred[0] + sqred[1] + sqred[2] + sqred[3];
        float mu = st * (1.f / D_MODEL);
        float var = sqt * (1.f / D_MODEL) - mu * mu;
        float rstd = rsqrtf(var + 1e-5f);
        u16* hr = h + (size_t)row * D_MODEL;
#pragma unroll
        for (int j = 0; j < 3; ++j) {
            int idx = tid + j * 256;
            hr[idx] = f2bf((v[j] - mu) * rstd * g[idx] + bln[idx]);
        }
        return;
    }
    int gid = (blockIdx.x - NROW) * 256 + tid;
    if (gid < N0) {
        float4 v = *(const float4*)(W_in + (size_t)gid * 4);
        u16* o = Win_bf + (size_t)gid * 4;
        o[0]=f2bf(v.x); o[1]=f2bf(v.y); o[2]=f2bf(v.z); o[3]=f2bf(v.w);
    } else if (gid < N0 + N1) {
        int i = gid - N0;
        float4 v = *(const float4*)(W_out + (size_t)i * 4);
        u16* o = Wout_bf + (size_t)i * 4;
        o[0]=f2bf(v.x); o[1]=f2bf(v.y); o[2]=f2bf(v.z); o[3]=f2bf(v.w);
    } else if (gid < N0 + N1 + N2) {
        int i = gid - N0 - N1;
        int n = (i * 4) / D_INNER, k = (i * 4) % D_INNER;
        u16* o = Wxp_bf + (size_t)i * 4;
        if (n < 80) {
            float4 v = *(const float4*)(W_xp + (size_t)n * D_INNER + k);
            o[0]=f2bf(v.x); o[1]=f2bf(v.y); o[2]=f2bf(v.z); o[3]=f2bf(v.w);
        } else { o[0]=0; o[1]=0; o[2]=0; o[3]=0; }
    } else if (gid < N0 + N1 + N2 + N3) {
        int i = gid - N0 - N1 - N2;
        int r = (i * 4) >> 6, c0 = (i * 4) & 63;
        u16* o = Wdt_bf + (size_t)i * 4;
        if (c0 < DT_RANK) {
            float4 v = *(const float4*)(W_dt + (size_t)r * DT_RANK + c0);
            o[0]=f2bf(v.x); o[1]=f2bf(v.y); o[2]=f2bf(v.z); o[3]=f2bf(v.w);
        } else { o[0]=0; o[1]=0; o[2]=0; o[3]=0; }
    } else if (gid < N0 + N1 + N2 + N3 + N4) {
        int i = gid - N0 - N1 - N2 - N3;
        float4 v = *(const float4*)(A_log + (size_t)i * 4);
        *(float4*)(negA + (size_t)i * 4) =
            make_float4(-__expf(v.x), -__expf(v.y), -__expf(v.z), -__expf(v.w));
    } else if (gid < N0 + N1 + N2 + N3 + N4 + N5) {
        int i = gid - N0 - N1 - N2 - N3 - N4;
        *(float4*)(xdbl + (size_t)i * 4) = make_float4(0.f, 0.f, 0.f, 0.f);
    }
}

// ============ m97-style MFMA GEMM: C(MxN) = A(MxK) * B(NxK)^T ==============
// ADD_RES: add f32 residual Res before store.
template<int MT, int NT, bool OUT_BF16, bool ADD_RES>
__global__ __launch_bounds__(256) void gemm128(
    const u16* __restrict__ A, const u16* __restrict__ B,
    const float* __restrict__ Res, void* __restrict__ Cv,
    int M, int N, int K)
{
    constexpr int BM = 32 * MT, BN = 32 * NT;
    __shared__ __align__(16) u16 As[BM * 32];
    __shared__ __align__(16) u16 Bs[BN * 32];
    int tid = threadIdx.x, w = tid >> 6, lane = tid & 63;
    int wm = w & 1, wn = w >> 1;
    int m0 = blockIdx.x * BM, n0 = blockIdx.y * BN;
    int mloc = lane & 15, quad = lane >> 4;
    int lr = lane >> 2, lc = lane & 3;
    f32x4 acc[MT][NT] = {};

    for (int k0 = 0; k0 < K; k0 += 32) {
        __syncthreads();
#pragma unroll
        for (int j = w; j < 2 * MT; j += 4) {
            int row = j * 16 + lr;
            int cb = lc ^ ((row >> 1) & 3);
            g2lds16(A + (size_t)(m0 + row) * K + k0 + cb * 8, &As[j * 512]);
        }
#pragma unroll
        for (int j = w; j < 2 * NT; j += 4) {
            int row = j * 16 + lr;
            int cb = lc ^ ((row >> 1) & 3);
            g2lds16(B + (size_t)(n0 + row) * K + k0 + cb * 8, &Bs[j * 512]);
        }
        __syncthreads();
        short8 afr[MT], bfr[NT];
#pragma unroll
        for (int mt = 0; mt < MT; ++mt) {
            int row = wm * MT * 16 + mt * 16 + mloc;
            int cb = quad ^ ((row >> 1) & 3);
            afr[mt] = *(const short8*)(&As[row * 32 + cb * 8]);
        }
#pragma unroll
        for (int nt = 0; nt < NT; ++nt) {
            int row = wn * NT * 16 + nt * 16 + mloc;
            int cb = quad ^ ((row >> 1) & 3);
            bfr[nt] = *(const short8*)(&Bs[row * 32 + cb * 8]);
        }
#pragma unroll
        for (int mt = 0; mt < MT; ++mt)
#pragma unroll
            for (int nt = 0; nt < NT; ++nt)
                acc[mt][nt] = __builtin_amdgcn_mfma_f32_16x16x32_bf16(
                    afr[mt], bfr[nt], acc[mt][nt], 0, 0, 0);
    }
    // C/D layout: col = lane&15, row = quad*4 + reg  [verified m89/m91]
#pragma unroll
    for (int mt = 0; mt < MT; ++mt) {
        int grow0 = m0 + wm * MT * 16 + mt * 16 + quad * 4;
#pragma unroll
        for (int nt = 0; nt < NT; ++nt) {
            int gcol = n0 + wn * NT * 16 + nt * 16 + mloc;
#pragma unroll
            for (int r = 0; r < 4; ++r) {
                size_t idx = (size_t)(grow0 + r) * N + gcol;
                float v = acc[mt][nt][r];
                if (ADD_RES) v += Res[idx];
                if (OUT_BF16) ((u16*)Cv)[idx] = f2bf(v);
                else          ((float*)Cv)[idx] = v;
            }
        }
    }
}

// ---------- split-K MFMA GEMM, f32 atomic-add epilogue (xproj only) --------
template<int MT, int NT, int KSLICE>
__global__ __launch_bounds__(256) void gemm_splitk(
    const u16* __restrict__ A, const u16* __restrict__ B,
    float* __restrict__ Cout, int K, int CS)
{
    constexpr int BM = 32 * MT, BN = 32 * NT;
    __shared__ __align__(16) u16 As[BM * 32];
    __shared__ __align__(16) u16 Bs[BN * 32];
    int tid = threadIdx.x, w = tid >> 6, lane = tid & 63;
    int wm = w & 1, wn = w >> 1;
    int m0 = blockIdx.x * BM, n0 = blockIdx.y * BN;
    int kbase = blockIdx.z * KSLICE;
    int mloc = lane & 15, quad = lane >> 4;
    int lr = lane >> 2, lc = lane & 3;
    f32x4 acc[MT][NT] = {};

    for (int k0 = 0; k0 < KSLICE; k0 += 32) {
        __syncthreads();
#pragma unroll
        for (int j = w; j < 2 * MT; j += 4) {
            int row = j * 16 + lr;
            int cb = lc ^ ((row >> 1) & 3);
            g2lds16(A + (size_t)(m0 + row) * K + kbase + k0 + cb * 8, &As[j * 512]);
        }
#pragma unroll
        for (int j = w; j < 2 * NT; j += 4) {
            int row = j * 16 + lr;
            int cb = lc ^ ((row >> 1) & 3);
            g2lds16(B + (size_t)(n0 + row) * K + kbase + k0 + cb * 8, &Bs[j * 512]);
        }
        __syncthreads();
        short8 afr[MT], bfr[NT];
#pragma unroll
        for (int mt = 0; mt < MT; ++mt) {
            int row = wm * MT * 16 + mt * 16 + mloc;
            int cb = quad ^ ((row >> 1) & 3);
            afr[mt] = *(const short8*)(&As[row * 32 + cb * 8]);
        }
#pragma unroll
        for (int nt = 0; nt < NT; ++nt) {
            int row = wn * NT * 16 + nt * 16 + mloc;
            int cb = quad ^ ((row >> 1) & 3);
            bfr[nt] = *(const short8*)(&Bs[row * 32 + cb * 8]);
        }
#pragma unroll
        for (int mt = 0; mt < MT; ++mt)
#pragma unroll
            for (int nt = 0; nt < NT; ++nt)
                acc[mt][nt] = __builtin_amdgcn_mfma_f32_16x16x32_bf16(
                    afr[mt], bfr[nt], acc[mt][nt], 0, 0, 0);
    }
#pragma unroll
    for (int mt = 0; mt < MT; ++mt) {
        int grow0 = m0 + wm * MT * 16 + mt * 16 + quad * 4;
#pragma unroll
        for (int nt = 0; nt < NT; ++nt) {
            int gcol = n0 + wn * NT * 16 + nt * 16 + mloc;
#pragma unroll
            for (int r = 0; r < 4; ++r)
                unsafeAtomicAdd(&Cout[(size_t)(grow0 + r) * CS + gcol],
                                acc[mt][nt][r]);
        }
    }
}

// ---------------- dt GEMM: dt = softplus(xdbl[:, :64] @ Wdt_pad^T + b) -----
__global__ __launch_bounds__(256) void dtgemm_k(
    const float* __restrict__ xdbl, const u16* __restrict__ Wdt,
    const float* __restrict__ bias, u16* __restrict__ dtout)
{
    __shared__ __align__(16) u16 Bs[64 * 72];
    int tid = threadIdx.x, wave = tid >> 6, lane = tid & 63;
    int m0 = blockIdx.x * 64, n0 = blockIdx.y * 64;
    int mloc = lane & 15, quad = lane >> 4;
    {
        int r = tid >> 3, ck = (tid & 7) * 8;
#pragma unroll
        for (int rr = 0; rr < 64; rr += 32) {
            int4 bv = *(const int4*)(Wdt + (size_t)(n0 + r + rr) * 64 + ck);
            *(int4*)(&Bs[(r + rr) * 72 + ck]) = bv;
        }
    }
    int arow = m0 + wave * 16 + mloc;
    const float* ar = xdbl + (size_t)arow * XDS + quad * 8;
    short8 af[2];
#pragma unroll
    for (int h = 0; h < 2; ++h) {
        float4 a0 = *(const float4*)(ar + h * 32);
        float4 a1 = *(const float4*)(ar + h * 32 + 4);
        short8 t;
        t[0]=(short)f2bf(a0.x); t[1]=(short)f2bf(a0.y);
        t[2]=(short)f2bf(a0.z); t[3]=(short)f2bf(a0.w);
        t[4]=(short)f2bf(a1.x); t[5]=(short)f2bf(a1.y);
        t[6]=(short)f2bf(a1.z); t[7]=(short)f2bf(a1.w);
        af[h] = t;
    }
    __syncthreads();
    f32x4 acc[4] = {};
#pragma unroll
    for (int h = 0; h < 2; ++h)
#pragma unroll
        for (int nt = 0; nt < 4; ++nt) {
            short8 bf = *(const short8*)(&Bs[(nt * 16 + mloc) * 72 + h * 32 + quad * 8]);
            acc[nt] = __builtin_amdgcn_mfma_f32_16x16x32_bf16(af[h], bf, acc[nt], 0, 0, 0);
        }
#pragma unroll
    for (int nt = 0; nt < 4; ++nt) {
        int gcol = n0 + nt * 16 + mloc;
        int grow = m0 + wave * 16 + quad * 4;
#pragma unroll
        for (int r = 0; r < 4; ++r) {
            float t = acc[nt][r] + bias[gcol];
            float sp = (t > 15.f) ? t : __logf(1.f + __expf(t));
            dtout[(size_t)(grow + r) * D_INNER + gcol] = f2bf(sp);
        }
    }
}

// ---------------- depthwise causal conv4 + SiLU (4-wide in c) --------------
__global__ __launch_bounds__(256) void conv_silu_k(
    const u16* __restrict__ xz, const float* __restrict__ cw,
    const float* __restrict__ cb, u16* __restrict__ xc)
{
    int gid = blockIdx.x * 256 + threadIdx.x;     // NROW * D_INNER/4
    int r = gid / (D_INNER / 4);
    int c4 = (gid - r * (D_INNER / 4)) * 4;
    int t = r & (SEQ - 1);
    float4 cbv = *(const float4*)(cb + c4);
    float acc[4] = {cbv.x, cbv.y, cbv.z, cbv.w};
    float4 wv[4];
#pragma unroll
    for (int j = 0; j < 4; ++j) wv[j] = *(const float4*)(cw + (c4 + j) * 4);
#pragma unroll
    for (int k = 0; k < 4; ++k) {
        int tt = t - 3 + k;
        if (tt >= 0) {
            ushort4 xv = *(const ushort4*)(xz + (size_t)(r - 3 + k) * D_XZ + c4);
            acc[0] += bf2f(xv.x) * ((const float*)&wv[0])[k];
            acc[1] += bf2f(xv.y) * ((const float*)&wv[1])[k];
            acc[2] += bf2f(xv.z) * ((const float*)&wv[2])[k];
            acc[3] += bf2f(xv.w) * ((const float*)&wv[3])[k];
        }
    }
    ushort4 o;
    o.x = f2bf(acc[0] / (1.f + __expf(-acc[0])));
    o.y = f2bf(acc[1] / (1.f + __expf(-acc[1])));
    o.z = f2bf(acc[2] / (1.f + __expf(-acc[2])));
    o.w = f2bf(acc[3] / (1.f + __expf(-acc[3])));
    *(ushort4*)(xc + (size_t)r * D_INNER + c4) = o;
}

// ====== chunked parallel scan (CLEN=16, bf16 S/carry, LDS-staged B/C) ======
__global__ __launch_bounds__(256) void scan_p1(
    const u16* __restrict__ dt, const u16* __restrict__ xc,
    const float* __restrict__ xdbl, const float* __restrict__ negA,
    u16* __restrict__ Sbuf, float* __restrict__ dtsumbuf)
{
    __shared__ float Bsh[CLEN][D_STATE];   // 16 rows x 16 B-vals
    int tid = threadIdx.x;
    int gid = blockIdx.x * 256 + tid;
    int d = gid % D_INNER;
    int bcN = gid / D_INNER;
    int c = bcN % NCHUNK, b = bcN / NCHUNK;
    size_t r0 = (size_t)b * SEQ + c * CLEN;
    {
        int tt = tid >> 4, n = tid & 15;   // 256 threads = 16x16 exactly
        Bsh[tt][n] = xdbl[(r0 + tt) * XDS + DT_RANK + n];
    }
    float a[D_STATE], s[D_STATE] = {};
    {
        const float4* Ar = (const float4*)(negA + d * D_STATE);
        float4 a0 = Ar[0], a1 = Ar[1], a2 = Ar[2], a3 = Ar[3];
        a[0]=a0.x; a[1]=a0.y; a[2]=a0.z; a[3]=a0.w;
        a[4]=a1.x; a[5]=a1.y; a[6]=a1.z; a[7]=a1.w;
        a[8]=a2.x; a[9]=a2.y; a[10]=a2.z; a[11]=a2.w;
        a[12]=a3.x; a[13]=a3.y; a[14]=a3.z; a[15]=a3.w;
    }
    float dtv[CLEN], du[CLEN];
    const u16* dp = dt + r0 * D_INNER + d;
    const u16* xp = xc + r0 * D_INNER + d;
#pragma unroll
    for (int t = 0; t < CLEN; ++t) {
        dtv[t] = bf2f(dp[t * D_INNER]);
        du[t] = dtv[t] * bf2f(xp[t * D_INNER]);
    }
    __syncthreads();
    float dtsum = 0.f;
#pragma unroll
    for (int t = 0; t < CLEN; ++t) {
        dtsum += dtv[t];
#pragma unroll
        for (int n = 0; n < D_STATE; ++n)
            s[n] = __expf(dtv[t] * a[n]) * s[n] + du[t] * Bsh[t][n];
    }
    ushort8 so[2];
#pragma unroll
    for (int j = 0; j < 16; ++j) so[j >> 3][j & 7] = f2bf(s[j]);
    *(ushort8*)(Sbuf + (size_t)gid * D_STATE) = so[0];
    *(ushort8*)(Sbuf + (size_t)gid * D_STATE + 8) = so[1];
    dtsumbuf[gid] = dtsum;
}

__global__ __launch_bounds__(256) void scan_p2(
    const u16* __restrict__ Sbuf, const float* __restrict__ dtsumbuf,
    const float* __restrict__ negA, u16* __restrict__ carry)
{
    int gid = blockIdx.x * 256 + threadIdx.x;   // B*D_INNER*16
    int n = gid % D_STATE;
    int d = (gid / D_STATE) % D_INNER;
    int b = gid / (D_STATE * D_INNER);
    float a = negA[d * D_STATE + n];
    float s = 0.f;
#pragma unroll 8
    for (int c = 0; c < NCHUNK; ++c) {
        size_t idx = ((size_t)(b * NCHUNK + c) * D_INNER + d);
        carry[idx * D_STATE + n] = f2bf(s);
        s = bf2f(Sbuf[idx * D_STATE + n]) + __expf(a * dtsumbuf[idx]) * s;
    }
}

__global__ __launch_bounds__(256) void scan_p3(
    const u16* __restrict__ dt, const u16* __restrict__ xc,
    const u16* __restrict__ xz, const float* __restrict__ xdbl,
    const float* __restrict__ negA, const float* __restrict__ Dp,
    const u16* __restrict__ carry, u16* __restrict__ yy)
{
    __shared__ float BCsh[CLEN][2 * D_STATE];   // 16 rows x (16 B | 16 C)
    int tid = threadIdx.x;
    int gid = blockIdx.x * 256 + tid;
    int d = gid % D_INNER;
    int bcN = gid / D_INNER;
    int c = bcN % NCHUNK, b = bcN / NCHUNK;
    size_t r0 = (size_t)b * SEQ + c * CLEN;
#pragma unroll
    for (int j = 0; j < 2; ++j) {
        int idx = tid + j * 256;
        int row = idx >> 5, col = idx & 31;   // 512 floats, 2/thread
        BCsh[row][col] = xdbl[(r0 + row) * XDS + DT_RANK + col];
    }
    float a[D_STATE], s[D_STATE];
    {
        ushort8 c0 = *(const ushort8*)(carry + (size_t)gid * D_STATE);
        ushort8 c1 = *(const ushort8*)(carry + (size_t)gid * D_STATE + 8);
#pragma unroll
        for (int j = 0; j < 8; ++j) { s[j] = bf2f(c0[j]); s[8 + j] = bf2f(c1[j]); }
        const float4* Ar = (const float4*)(negA + d * D_STATE);
        float4 a0 = Ar[0], a1 = Ar[1], a2 = Ar[2], a3 = Ar[3];
        a[0]=a0.x; a[1]=a0.y; a[2]=a0.z; a[3]=a0.w;
        a[4]=a1.x; a[5]=a1.y; a[6]=a1.z; a[7]=a1.w;
        a[8]=a2.x; a[9]=a2.y; a[10]=a2.z; a[11]=a2.w;
        a[12]=a3.x; a[13]=a3.y; a[14]=a3.z; a[15]=a3.w;
    }
    float dtv[CLEN], xcv[CLEN], zv[CLEN];
    const u16* dp = dt + r0 * D_INNER + d;
    const u16* xp = xc + r0 * D_INNER + d;
    const u16* zp = xz + r0 * D_XZ + D_INNER + d;
#pragma unroll
    for (int t = 0; t < CLEN; ++t) {
        dtv[t] = bf2f(dp[t * D_INNER]);
        xcv[t] = bf2f(xp[t * D_INNER]);
        zv[t]  = bf2f(zp[t * D_XZ]);
    }
    float dpv = Dp[d];
    __syncthreads();
    u16* yp = yy + r0 * D_INNER + d;
#pragma unroll
    for (int t = 0; t < CLEN; ++t) {
        float du = dtv[t] * xcv[t];
        float y = 0.f;
#pragma unroll
        for (int n = 0; n < D_STATE; ++n) {
            s[n] = __expf(dtv[t] * a[n]) * s[n] + du * BCsh[t][n];
            y += s[n] * BCsh[t][D_STATE + n];
        }
        float yv = y + dpv * xcv[t];
        float sig = 1.f / (1.f + __expf(-zv[t]));
        yp[t * D_INNER] = f2bf(yv * (zv[t] * sig));
    }
}

extern "C" void kernel_launch(void* const* d_in, const int* in_sizes, int n_in,
                              void* d_out, int out_size, void* d_ws, size_t ws_size,
                              hipStream_t stream) {
    const float* x      = (const float*)d_in[0];
    const float* ln_g   = (const float*)d_in[1];
    const float* ln_b   = (const float*)d_in[2];
    const float* W_in   = (const float*)d_in[3];
    const float* conv_w = (const float*)d_in[4];
    const float* conv_b = (const float*)d_in[5];
    const float* W_xp   = (const float*)d_in[6];
    const float* W_dt   = (const float*)d_in[7];
    const float* b_dt   = (const float*)d_in[8];
    const float* A_log  = (const float*)d_in[9];
    const float* Dp     = (const float*)d_in[10];
    const float* W_out  = (const float*)d_in[11];
    float* out = (float*)d_out;

    char* ws = (char*)d_ws;
    u16*   h_bf    = (u16*)ws;   ws += (size_t)NROW * D_MODEL * 2;
    u16*   xz_bf   = (u16*)ws;   ws += (size_t)NROW * D_XZ * 2;
    u16*   xc_bf   = (u16*)ws;   ws += (size_t)NROW * D_INNER * 2;
    float* xdbl    = (float*)ws; ws += (size_t)NROW * XDS * 4;
    u16*   dtbuf   = (u16*)ws;   ws += (size_t)NROW * D_INNER * 2;
    u16*   yybuf   = (u16*)ws;   ws += (size_t)NROW * D_INNER * 2;
    u16*   Win_bf  = (u16*)ws;   ws += (size_t)D_XZ * D_MODEL * 2;
    u16*   Wout_bf = (u16*)ws;   ws += (size_t)D_MODEL * D_INNER * 2;
    u16*   Wxp_bf  = (u16*)ws;   ws += (size_t)XDS * D_INNER * 2;
    u16*   Wdt_bf  = (u16*)ws;   ws += (size_t)D_INNER * 64 * 2;
    float* negA    = (float*)ws; ws += (size_t)D_INNER * D_STATE * 4;
    u16*   Sbuf    = (u16*)ws;   ws += (size_t)2 * NCHUNK * D_INNER * 16 * 2;
    float* dtsumb  = (float*)ws; ws += (size_t)2 * NCHUNK * D_INNER * 4;
    u16*   carryb  = (u16*)ws;

    // prep: LN rows (2048 blocks) + weight-convert/zeroing (4024 blocks)
    prep_ln_k<<<NROW + PREP_BLOCKS, 256, 0, stream>>>(
        x, ln_g, ln_b, h_bf, W_in, W_out, W_xp, W_dt, A_log,
        Win_bf, Wout_bf, Wxp_bf, Wdt_bf, negA, xdbl);

    // GEMM1: 2048x3072x768, 128x64 tiles -> 768 blocks (3/CU)
    gemm128<4, 2, true, false><<<dim3(NROW / 128, D_XZ / 64), 256, 0, stream>>>(
        h_bf, Win_bf, nullptr, xz_bf, NROW, D_XZ, D_MODEL);
    conv_silu_k<<<NROW * (D_INNER / 4) / 256, 256, 0, stream>>>(
        xz_bf, conv_w, conv_b, xc_bf);
    // xproj: 64x128 tile, split-K x8 (slice 192) -> 256 blocks
    gemm_splitk<2, 4, 192><<<dim3(NROW / 64, 1, 8), 256, 0, stream>>>(
        xc_bf, Wxp_bf, xdbl, D_INNER, XDS);
    // dt: 2048x1536x64, bf16 out; 768 blocks
    dtgemm_k<<<dim3(NROW / 64, D_INNER / 64), 256, 0, stream>>>(
        xdbl, Wdt_bf, b_dt, dtbuf);

    scan_p1<<<2 * NCHUNK * D_INNER / 256, 256, 0, stream>>>(
        dtbuf, xc_bf, xdbl, negA, Sbuf, dtsumb);
    scan_p2<<<2 * D_INNER * D_STATE / 256, 256, 0, stream>>>(
        Sbuf, dtsumb, negA, carryb);
    scan_p3<<<2 * NCHUNK * D_INNER / 256, 256, 0, stream>>>(
        dtbuf, xc_bf, xz_bf, xdbl, negA, Dp, carryb, yybuf);

    // GEMM-out: 2048x768x1536, 64x64 tiles -> 384 blocks, fused +x residual
    gemm128<2, 2, false, true><<<dim3(NROW / 64, D_MODEL / 64), 256, 0, stream>>>(
        yybuf, Wout_bf, x, out, NROW, D_MODEL, D_INNER);
}

// Round 11
// 186.180 us; speedup vs baseline: 2.7559x; 1.0458x over previous
//
#include <hip/hip_runtime.h>

typedef unsigned short u16;
typedef unsigned int u32;
typedef __attribute__((ext_vector_type(8))) short short8;
typedef __attribute__((ext_vector_type(8))) unsigned short ushort8;
typedef __attribute__((ext_vector_type(4))) float f32x4;

#define D_MODEL 768
#define D_INNER 1536
#define D_XZ    3072
#define D_STATE 16
#define DT_RANK 48
#define NROW    2048   // B*T
#define SEQ     1024
#define XDS     128    // padded x_dbl row stride (48 dt_r | 16 B | 16 C | pad)
#define NCHUNK  64
#define CLEN    16     // SEQ / NCHUNK; 768 blocks = 3/CU (don't go below 2/CU: r5)

typedef const __attribute__((address_space(1))) u32 glb_u32;
typedef __attribute__((address_space(3))) u32 lds_u32;

__device__ __forceinline__ float bf2f(u16 u) {
    union { unsigned int i; float f; } v; v.i = ((unsigned int)u) << 16; return v.f;
}
__device__ __forceinline__ u16 f2bf(float f) {
    union { float f; unsigned int i; } v; v.f = f;
    unsigned int r = v.i + 0x7fffu + ((v.i >> 16) & 1u);
    return (u16)(r >> 16);
}
__device__ __forceinline__ void g2lds16(const u16* g, u16* l) {
    __builtin_amdgcn_global_load_lds((glb_u32*)g, (lds_u32*)l, 16, 0, 0);
}

// ======== fused prep: LayerNorm (blocks 0..2047) + weight prep/zeroing =====
// NOTE: no cooperative anything — grid.sync() on MI355X flushes per-XCD L2
// (measured r8: 345 MB HBM traffic, 315 µs). Separate kernels are cheaper.
#define N0 (D_XZ * D_MODEL / 4)        // 589824  Win->bf16
#define N1 (D_MODEL * D_INNER / 4)     // 294912  Wout->bf16
#define N2 (XDS * D_INNER / 4)         // 49152   Wxp pad128->bf16
#define N3 (D_INNER * 64 / 4)          // 24576   Wdt pad64->bf16
#define N4 (D_INNER * D_STATE / 4)     // 6144    negA
#define N5 (NROW * XDS / 4)            // 65536   zero xdbl
#define PREP_BLOCKS ((N0+N1+N2+N3+N4+N5) / 256)   // 4024
__global__ __launch_bounds__(256) void prep_ln_k(
    const float* __restrict__ x, const float* __restrict__ g,
    const float* __restrict__ bln, u16* __restrict__ h,
    const float* __restrict__ W_in, const float* __restrict__ W_out,
    const float* __restrict__ W_xp, const float* __restrict__ W_dt,
    const float* __restrict__ A_log,
    u16* __restrict__ Win_bf, u16* __restrict__ Wout_bf,
    u16* __restrict__ Wxp_bf, u16* __restrict__ Wdt_bf,
    float* __restrict__ negA, float* __restrict__ xdbl)
{
    __shared__ float sred[4], sqred[4];
    int tid = threadIdx.x;
    if (blockIdx.x < NROW) {
        int row = blockIdx.x;
        const float* xr = x + (size_t)row * D_MODEL;
        float v[3], s = 0.f, sq = 0.f;
#pragma unroll
        for (int j = 0; j < 3; ++j) {
            v[j] = xr[tid + j * 256];
            s += v[j]; sq += v[j] * v[j];
        }
#pragma unroll
        for (int off = 32; off >= 1; off >>= 1) {
            s  += __shfl_xor(s,  off, 64);
            sq += __shfl_xor(sq, off, 64);
        }
        if ((tid & 63) == 0) { sred[tid >> 6] = s; sqred[tid >> 6] = sq; }
        __syncthreads();
        float st = sred[0] + sred[1] + sred[2] + sred[3];
        float sqt = sqred[0] + sqred[1] + sqred[2] + sqred[3];
        float mu = st * (1.f / D_MODEL);
        float var = sqt * (1.f / D_MODEL) - mu * mu;
        float rstd = rsqrtf(var + 1e-5f);
        u16* hr = h + (size_t)row * D_MODEL;
#pragma unroll
        for (int j = 0; j < 3; ++j) {
            int idx = tid + j * 256;
            hr[idx] = f2bf((v[j] - mu) * rstd * g[idx] + bln[idx]);
        }
        return;
    }
    int gid = (blockIdx.x - NROW) * 256 + tid;
    if (gid < N0) {
        float4 v = *(const float4*)(W_in + (size_t)gid * 4);
        u16* o = Win_bf + (size_t)gid * 4;
        o[0]=f2bf(v.x); o[1]=f2bf(v.y); o[2]=f2bf(v.z); o[3]=f2bf(v.w);
    } else if (gid < N0 + N1) {
        int i = gid - N0;
        float4 v = *(const float4*)(W_out + (size_t)i * 4);
        u16* o = Wout_bf + (size_t)i * 4;
        o[0]=f2bf(v.x); o[1]=f2bf(v.y); o[2]=f2bf(v.z); o[3]=f2bf(v.w);
    } else if (gid < N0 + N1 + N2) {
        int i = gid - N0 - N1;
        int n = (i * 4) / D_INNER, k = (i * 4) % D_INNER;
        u16* o = Wxp_bf + (size_t)i * 4;
        if (n < 80) {
            float4 v = *(const float4*)(W_xp + (size_t)n * D_INNER + k);
            o[0]=f2bf(v.x); o[1]=f2bf(v.y); o[2]=f2bf(v.z); o[3]=f2bf(v.w);
        } else { o[0]=0; o[1]=0; o[2]=0; o[3]=0; }
    } else if (gid < N0 + N1 + N2 + N3) {
        int i = gid - N0 - N1 - N2;
        int r = (i * 4) >> 6, c0 = (i * 4) & 63;
        u16* o = Wdt_bf + (size_t)i * 4;
        if (c0 < DT_RANK) {
            float4 v = *(const float4*)(W_dt + (size_t)r * DT_RANK + c0);
            o[0]=f2bf(v.x); o[1]=f2bf(v.y); o[2]=f2bf(v.z); o[3]=f2bf(v.w);
        } else { o[0]=0; o[1]=0; o[2]=0; o[3]=0; }
    } else if (gid < N0 + N1 + N2 + N3 + N4) {
        int i = gid - N0 - N1 - N2 - N3;
        float4 v = *(const float4*)(A_log + (size_t)i * 4);
        *(float4*)(negA + (size_t)i * 4) =
            make_float4(-__expf(v.x), -__expf(v.y), -__expf(v.z), -__expf(v.w));
    } else if (gid < N0 + N1 + N2 + N3 + N4 + N5) {
        int i = gid - N0 - N1 - N2 - N3 - N4;
        *(float4*)(xdbl + (size_t)i * 4) = make_float4(0.f, 0.f, 0.f, 0.f);
    }
}

// ============ m97-style MFMA GEMM, BK=64: C(MxN) = A(MxK) * B(NxK)^T =======
// 4 waves in 2x2; wave tile (MT*16)x(NT*16); BM=32*MT, BN=32*NT.
// BK=64 halves barrier count vs BK=32 (16 MFMA per barrier-pair at MT4/NT2).
// LDS row stride = 64 u16 = 32 banks (row-independent bank base), so swizzle
// is global-side chunk permute cg = lc ^ (row&7) on store (g2lds16 dest is
// HW base+lane*16, can't scatter) and pc = (h*4+quad) ^ (row&7) on read ->
// 8 bank groups / 16 lanes = 2-way aliasing = free [m136].
template<int MT, int NT, bool OUT_BF16, bool ADD_RES>
__global__ __launch_bounds__(256) void gemm128(
    const u16* __restrict__ A, const u16* __restrict__ B,
    const float* __restrict__ Res, void* __restrict__ Cv,
    int M, int N, int K)
{
    constexpr int BM = 32 * MT, BN = 32 * NT;
    __shared__ __align__(16) u16 As[BM * 64];
    __shared__ __align__(16) u16 Bs[BN * 64];
    int tid = threadIdx.x, w = tid >> 6, lane = tid & 63;
    int wm = w & 1, wn = w >> 1;
    int m0 = blockIdx.x * BM, n0 = blockIdx.y * BN;
    int mloc = lane & 15, quad = lane >> 4;
    int lr8 = lane >> 3, lc8 = lane & 7;
    f32x4 acc[MT][NT] = {};

    for (int k0 = 0; k0 < K; k0 += 64) {
        __syncthreads();
#pragma unroll
        for (int j = w; j < BM / 8; j += 4) {
            int row = j * 8 + lr8;
            int cg = lc8 ^ (row & 7);
            g2lds16(A + (size_t)(m0 + row) * K + k0 + cg * 8, &As[j * 512]);
        }
#pragma unroll
        for (int j = w; j < BN / 8; j += 4) {
            int row = j * 8 + lr8;
            int cg = lc8 ^ (row & 7);
            g2lds16(B + (size_t)(n0 + row) * K + k0 + cg * 8, &Bs[j * 512]);
        }
        __syncthreads();
        short8 afr[MT][2], bfr[NT][2];
#pragma unroll
        for (int mt = 0; mt < MT; ++mt) {
            int row = wm * MT * 16 + mt * 16 + mloc;
#pragma unroll
            for (int h = 0; h < 2; ++h) {
                int pc = (h * 4 + quad) ^ (row & 7);
                afr[mt][h] = *(const short8*)(&As[row * 64 + pc * 8]);
            }
        }
#pragma unroll
        for (int nt = 0; nt < NT; ++nt) {
            int row = wn * NT * 16 + nt * 16 + mloc;
#pragma unroll
            for (int h = 0; h < 2; ++h) {
                int pc = (h * 4 + quad) ^ (row & 7);
                bfr[nt][h] = *(const short8*)(&Bs[row * 64 + pc * 8]);
            }
        }
#pragma unroll
        for (int h = 0; h < 2; ++h)
#pragma unroll
            for (int mt = 0; mt < MT; ++mt)
#pragma unroll
                for (int nt = 0; nt < NT; ++nt)
                    acc[mt][nt] = __builtin_amdgcn_mfma_f32_16x16x32_bf16(
                        afr[mt][h], bfr[nt][h], acc[mt][nt], 0, 0, 0);
    }
    // C/D layout: col = lane&15, row = quad*4 + reg  [verified m89/m91]
#pragma unroll
    for (int mt = 0; mt < MT; ++mt) {
        int grow0 = m0 + wm * MT * 16 + mt * 16 + quad * 4;
#pragma unroll
        for (int nt = 0; nt < NT; ++nt) {
            int gcol = n0 + wn * NT * 16 + nt * 16 + mloc;
#pragma unroll
            for (int r = 0; r < 4; ++r) {
                size_t idx = (size_t)(grow0 + r) * N + gcol;
                float v = acc[mt][nt][r];
                if (ADD_RES) v += Res[idx];
                if (OUT_BF16) ((u16*)Cv)[idx] = f2bf(v);
                else          ((float*)Cv)[idx] = v;
            }
        }
    }
}

// ---------- split-K MFMA GEMM (BK=64), f32 atomic-add epilogue (xproj) -----
template<int MT, int NT, int KSLICE>
__global__ __launch_bounds__(256) void gemm_splitk(
    const u16* __restrict__ A, const u16* __restrict__ B,
    float* __restrict__ Cout, int K, int CS)
{
    constexpr int BM = 32 * MT, BN = 32 * NT;
    __shared__ __align__(16) u16 As[BM * 64];
    __shared__ __align__(16) u16 Bs[BN * 64];
    int tid = threadIdx.x, w = tid >> 6, lane = tid & 63;
    int wm = w & 1, wn = w >> 1;
    int m0 = blockIdx.x * BM, n0 = blockIdx.y * BN;
    int kbase = blockIdx.z * KSLICE;
    int mloc = lane & 15, quad = lane >> 4;
    int lr8 = lane >> 3, lc8 = lane & 7;
    f32x4 acc[MT][NT] = {};

    for (int k0 = 0; k0 < KSLICE; k0 += 64) {
        __syncthreads();
#pragma unroll
        for (int j = w; j < BM / 8; j += 4) {
            int row = j * 8 + lr8;
            int cg = lc8 ^ (row & 7);
            g2lds16(A + (size_t)(m0 + row) * K + kbase + k0 + cg * 8, &As[j * 512]);
        }
#pragma unroll
        for (int j = w; j < BN / 8; j += 4) {
            int row = j * 8 + lr8;
            int cg = lc8 ^ (row & 7);
            g2lds16(B + (size_t)(n0 + row) * K + kbase + k0 + cg * 8, &Bs[j * 512]);
        }
        __syncthreads();
        short8 afr[MT][2], bfr[NT][2];
#pragma unroll
        for (int mt = 0; mt < MT; ++mt) {
            int row = wm * MT * 16 + mt * 16 + mloc;
#pragma unroll
            for (int h = 0; h < 2; ++h) {
                int pc = (h * 4 + quad) ^ (row & 7);
                afr[mt][h] = *(const short8*)(&As[row * 64 + pc * 8]);
            }
        }
#pragma unroll
        for (int nt = 0; nt < NT; ++nt) {
            int row = wn * NT * 16 + nt * 16 + mloc;
#pragma unroll
            for (int h = 0; h < 2; ++h) {
                int pc = (h * 4 + quad) ^ (row & 7);
                bfr[nt][h] = *(const short8*)(&Bs[row * 64 + pc * 8]);
            }
        }
#pragma unroll
        for (int h = 0; h < 2; ++h)
#pragma unroll
            for (int mt = 0; mt < MT; ++mt)
#pragma unroll
                for (int nt = 0; nt < NT; ++nt)
                    acc[mt][nt] = __builtin_amdgcn_mfma_f32_16x16x32_bf16(
                        afr[mt][h], bfr[nt][h], acc[mt][nt], 0, 0, 0);
    }
#pragma unroll
    for (int mt = 0; mt < MT; ++mt) {
        int grow0 = m0 + wm * MT * 16 + mt * 16 + quad * 4;
#pragma unroll
        for (int nt = 0; nt < NT; ++nt) {
            int gcol = n0 + wn * NT * 16 + nt * 16 + mloc;
#pragma unroll
            for (int r = 0; r < 4; ++r)
                unsafeAtomicAdd(&Cout[(size_t)(grow0 + r) * CS + gcol],
                                acc[mt][nt][r]);
        }
    }
}

// ---------------- dt GEMM: dt = softplus(xdbl[:, :64] @ Wdt_pad^T + b) -----
__global__ __launch_bounds__(256) void dtgemm_k(
    const float* __restrict__ xdbl, const u16* __restrict__ Wdt,
    const float* __restrict__ bias, u16* __restrict__ dtout)
{
    __shared__ __align__(16) u16 Bs[64 * 72];
    int tid = threadIdx.x, wave = tid >> 6, lane = tid & 63;
    int m0 = blockIdx.x * 64, n0 = blockIdx.y * 64;
    int mloc = lane & 15, quad = lane >> 4;
    {
        int r = tid >> 3, ck = (tid & 7) * 8;
#pragma unroll
        for (int rr = 0; rr < 64; rr += 32) {
            int4 bv = *(const int4*)(Wdt + (size_t)(n0 + r + rr) * 64 + ck);
            *(int4*)(&Bs[(r + rr) * 72 + ck]) = bv;
        }
    }
    int arow = m0 + wave * 16 + mloc;
    const float* ar = xdbl + (size_t)arow * XDS + quad * 8;
    short8 af[2];
#pragma unroll
    for (int h = 0; h < 2; ++h) {
        float4 a0 = *(const float4*)(ar + h * 32);
        float4 a1 = *(const float4*)(ar + h * 32 + 4);
        short8 t;
        t[0]=(short)f2bf(a0.x); t[1]=(short)f2bf(a0.y);
        t[2]=(short)f2bf(a0.z); t[3]=(short)f2bf(a0.w);
        t[4]=(short)f2bf(a1.x); t[5]=(short)f2bf(a1.y);
        t[6]=(short)f2bf(a1.z); t[7]=(short)f2bf(a1.w);
        af[h] = t;
    }
    __syncthreads();
    f32x4 acc[4] = {};
#pragma unroll
    for (int h = 0; h < 2; ++h)
#pragma unroll
        for (int nt = 0; nt < 4; ++nt) {
            short8 bf = *(const short8*)(&Bs[(nt * 16 + mloc) * 72 + h * 32 + quad * 8]);
            acc[nt] = __builtin_amdgcn_mfma_f32_16x16x32_bf16(af[h], bf, acc[nt], 0, 0, 0);
        }
#pragma unroll
    for (int nt = 0; nt < 4; ++nt) {
        int gcol = n0 + nt * 16 + mloc;
        int grow = m0 + wave * 16 + quad * 4;
#pragma unroll
        for (int r = 0; r < 4; ++r) {
            float t = acc[nt][r] + bias[gcol];
            float sp = (t > 15.f) ? t : __logf(1.f + __expf(t));
            dtout[(size_t)(grow + r) * D_INNER + gcol] = f2bf(sp);
        }
    }
}

// ---------------- depthwise causal conv4 + SiLU (4-wide in c) --------------
__global__ __launch_bounds__(256) void conv_silu_k(
    const u16* __restrict__ xz, const float* __restrict__ cw,
    const float* __restrict__ cb, u16* __restrict__ xc)
{
    int gid = blockIdx.x * 256 + threadIdx.x;     // NROW * D_INNER/4
    int r = gid / (D_INNER / 4);
    int c4 = (gid - r * (D_INNER / 4)) * 4;
    int t = r & (SEQ - 1);
    float4 cbv = *(const float4*)(cb + c4);
    float acc[4] = {cbv.x, cbv.y, cbv.z, cbv.w};
    float4 wv[4];
#pragma unroll
    for (int j = 0; j < 4; ++j) wv[j] = *(const float4*)(cw + (c4 + j) * 4);
#pragma unroll
    for (int k = 0; k < 4; ++k) {
        int tt = t - 3 + k;
        if (tt >= 0) {
            ushort4 xv = *(const ushort4*)(xz + (size_t)(r - 3 + k) * D_XZ + c4);
            acc[0] += bf2f(xv.x) * ((const float*)&wv[0])[k];
            acc[1] += bf2f(xv.y) * ((const float*)&wv[1])[k];
            acc[2] += bf2f(xv.z) * ((const float*)&wv[2])[k];
            acc[3] += bf2f(xv.w) * ((const float*)&wv[3])[k];
        }
    }
    ushort4 o;
    o.x = f2bf(acc[0] / (1.f + __expf(-acc[0])));
    o.y = f2bf(acc[1] / (1.f + __expf(-acc[1])));
    o.z = f2bf(acc[2] / (1.f + __expf(-acc[2])));
    o.w = f2bf(acc[3] / (1.f + __expf(-acc[3])));
    *(ushort4*)(xc + (size_t)r * D_INNER + c4) = o;
}

// ====== chunked parallel scan (CLEN=16, bf16 S/carry, LDS-staged B/C) ======
__global__ __launch_bounds__(256) void scan_p1(
    const u16* __restrict__ dt, const u16* __restrict__ xc,
    const float* __restrict__ xdbl, const float* __restrict__ negA,
    u16* __restrict__ Sbuf, float* __restrict__ dtsumbuf)
{
    __shared__ float Bsh[CLEN][D_STATE];   // 16 rows x 16 B-vals
    int tid = threadIdx.x;
    int gid = blockIdx.x * 256 + tid;
    int d = gid % D_INNER;
    int bcN = gid / D_INNER;
    int c = bcN % NCHUNK, b = bcN / NCHUNK;
    size_t r0 = (size_t)b * SEQ + c * CLEN;
    {
        int tt = tid >> 4, n = tid & 15;   // 256 threads = 16x16 exactly
        Bsh[tt][n] = xdbl[(r0 + tt) * XDS + DT_RANK + n];
    }
    float a[D_STATE], s[D_STATE] = {};
    {
        const float4* Ar = (const float4*)(negA + d * D_STATE);
        float4 a0 = Ar[0], a1 = Ar[1], a2 = Ar[2], a3 = Ar[3];
        a[0]=a0.x; a[1]=a0.y; a[2]=a0.z; a[3]=a0.w;
        a[4]=a1.x; a[5]=a1.y; a[6]=a1.z; a[7]=a1.w;
        a[8]=a2.x; a[9]=a2.y; a[10]=a2.z; a[11]=a2.w;
        a[12]=a3.x; a[13]=a3.y; a[14]=a3.z; a[15]=a3.w;
    }
    float dtv[CLEN], du[CLEN];
    const u16* dp = dt + r0 * D_INNER + d;
    const u16* xp = xc + r0 * D_INNER + d;
#pragma unroll
    for (int t = 0; t < CLEN; ++t) {
        dtv[t] = bf2f(dp[t * D_INNER]);
        du[t] = dtv[t] * bf2f(xp[t * D_INNER]);
    }
    __syncthreads();
    float dtsum = 0.f;
#pragma unroll
    for (int t = 0; t < CLEN; ++t) {
        dtsum += dtv[t];
#pragma unroll
        for (int n = 0; n < D_STATE; ++n)
            s[n] = __expf(dtv[t] * a[n]) * s[n] + du[t] * Bsh[t][n];
    }
    ushort8 so[2];
#pragma unroll
    for (int j = 0; j < 16; ++j) so[j >> 3][j & 7] = f2bf(s[j]);
    *(ushort8*)(Sbuf + (size_t)gid * D_STATE) = so[0];
    *(ushort8*)(Sbuf + (size_t)gid * D_STATE + 8) = so[1];
    dtsumbuf[gid] = dtsum;
}

__global__ __launch_bounds__(256) void scan_p2(
    const u16* __restrict__ Sbuf, const float* __restrict__ dtsumbuf,
    const float* __restrict__ negA, u16* __restrict__ carry)
{
    int gid = blockIdx.x * 256 + threadIdx.x;   // B*D_INNER*16
    int n = gid % D_STATE;
    int d = (gid / D_STATE) % D_INNER;
    int b = gid / (D_STATE * D_INNER);
    float a = negA[d * D_STATE + n];
    float s = 0.f;
#pragma unroll 8
    for (int c = 0; c < NCHUNK; ++c) {
        size_t idx = ((size_t)(b * NCHUNK + c) * D_INNER + d);
        carry[idx * D_STATE + n] = f2bf(s);
        s = bf2f(Sbuf[idx * D_STATE + n]) + __expf(a * dtsumbuf[idx]) * s;
    }
}

__global__ __launch_bounds__(256) void scan_p3(
    const u16* __restrict__ dt, const u16* __restrict__ xc,
    const u16* __restrict__ xz, const float* __restrict__ xdbl,
    const float* __restrict__ negA, const float* __restrict__ Dp,
    const u16* __restrict__ carry, u16* __restrict__ yy)
{
    __shared__ float BCsh[CLEN][2 * D_STATE];   // 16 rows x (16 B | 16 C)
    int tid = threadIdx.x;
    int gid = blockIdx.x * 256 + tid;
    int d = gid % D_INNER;
    int bcN = gid / D_INNER;
    int c = bcN % NCHUNK, b = bcN / NCHUNK;
    size_t r0 = (size_t)b * SEQ + c * CLEN;
#pragma unroll
    for (int j = 0; j < 2; ++j) {
        int idx = tid + j * 256;
        int row = idx >> 5, col = idx & 31;   // 512 floats, 2/thread
        BCsh[row][col] = xdbl[(r0 + row) * XDS + DT_RANK + col];
    }
    float a[D_STATE], s[D_STATE];
    {
        ushort8 c0 = *(const ushort8*)(carry + (size_t)gid * D_STATE);
        ushort8 c1 = *(const ushort8*)(carry + (size_t)gid * D_STATE + 8);
#pragma unroll
        for (int j = 0; j < 8; ++j) { s[j] = bf2f(c0[j]); s[8 + j] = bf2f(c1[j]); }
        const float4* Ar = (const float4*)(negA + d * D_STATE);
        float4 a0 = Ar[0], a1 = Ar[1], a2 = Ar[2], a3 = Ar[3];
        a[0]=a0.x; a[1]=a0.y; a[2]=a0.z; a[3]=a0.w;
        a[4]=a1.x; a[5]=a1.y; a[6]=a1.z; a[7]=a1.w;
        a[8]=a2.x; a[9]=a2.y; a[10]=a2.z; a[11]=a2.w;
        a[12]=a3.x; a[13]=a3.y; a[14]=a3.z; a[15]=a3.w;
    }
    float dtv[CLEN], xcv[CLEN], zv[CLEN];
    const u16* dp = dt + r0 * D_INNER + d;
    const u16* xp = xc + r0 * D_INNER + d;
    const u16* zp = xz + r0 * D_XZ + D_INNER + d;
#pragma unroll
    for (int t = 0; t < CLEN; ++t) {
        dtv[t] = bf2f(dp[t * D_INNER]);
        xcv[t] = bf2f(xp[t * D_INNER]);
        zv[t]  = bf2f(zp[t * D_XZ]);
    }
    float dpv = Dp[d];
    __syncthreads();
    u16* yp = yy + r0 * D_INNER + d;
#pragma unroll
    for (int t = 0; t < CLEN; ++t) {
        float du = dtv[t] * xcv[t];
        float y = 0.f;
#pragma unroll
        for (int n = 0; n < D_STATE; ++n) {
            s[n] = __expf(dtv[t] * a[n]) * s[n] + du * BCsh[t][n];
            y += s[n] * BCsh[t][D_STATE + n];
        }
        float yv = y + dpv * xcv[t];
        float sig = 1.f / (1.f + __expf(-zv[t]));
        yp[t * D_INNER] = f2bf(yv * (zv[t] * sig));
    }
}

extern "C" void kernel_launch(void* const* d_in, const int* in_sizes, int n_in,
                              void* d_out, int out_size, void* d_ws, size_t ws_size,
                              hipStream_t stream) {
    const float* x      = (const float*)d_in[0];
    const float* ln_g   = (const float*)d_in[1];
    const float* ln_b   = (const float*)d_in[2];
    const float* W_in   = (const float*)d_in[3];
    const float* conv_w = (const float*)d_in[4];
    const float* conv_b = (const float*)d_in[5];
    const float* W_xp   = (const float*)d_in[6];
    const float* W_dt   = (const float*)d_in[7];
    const float* b_dt   = (const float*)d_in[8];
    const float* A_log  = (const float*)d_in[9];
    const float* Dp     = (const float*)d_in[10];
    const float* W_out  = (const float*)d_in[11];
    float* out = (float*)d_out;

    char* ws = (char*)d_ws;
    u16*   h_bf    = (u16*)ws;   ws += (size_t)NROW * D_MODEL * 2;
    u16*   xz_bf   = (u16*)ws;   ws += (size_t)NROW * D_XZ * 2;
    u16*   xc_bf   = (u16*)ws;   ws += (size_t)NROW * D_INNER * 2;
    float* xdbl    = (float*)ws; ws += (size_t)NROW * XDS * 4;
    u16*   dtbuf   = (u16*)ws;   ws += (size_t)NROW * D_INNER * 2;
    u16*   yybuf   = (u16*)ws;   ws += (size_t)NROW * D_INNER * 2;
    u16*   Win_bf  = (u16*)ws;   ws += (size_t)D_XZ * D_MODEL * 2;
    u16*   Wout_bf = (u16*)ws;   ws += (size_t)D_MODEL * D_INNER * 2;
    u16*   Wxp_bf  = (u16*)ws;   ws += (size_t)XDS * D_INNER * 2;
    u16*   Wdt_bf  = (u16*)ws;   ws += (size_t)D_INNER * 64 * 2;
    float* negA    = (float*)ws; ws += (size_t)D_INNER * D_STATE * 4;
    u16*   Sbuf    = (u16*)ws;   ws += (size_t)2 * NCHUNK * D_INNER * 16 * 2;
    float* dtsumb  = (float*)ws; ws += (size_t)2 * NCHUNK * D_INNER * 4;
    u16*   carryb  = (u16*)ws;

    // prep: LN rows (2048 blocks) + weight-convert/zeroing (4024 blocks)
    prep_ln_k<<<NROW + PREP_BLOCKS, 256, 0, stream>>>(
        x, ln_g, ln_b, h_bf, W_in, W_out, W_xp, W_dt, A_log,
        Win_bf, Wout_bf, Wxp_bf, Wdt_bf, negA, xdbl);

    // GEMM1: 2048x3072x768, 128x64 tiles, BK=64 -> 768 blocks (3/CU)
    gemm128<4, 2, true, false><<<dim3(NROW / 128, D_XZ / 64), 256, 0, stream>>>(
        h_bf, Win_bf, nullptr, xz_bf, NROW, D_XZ, D_MODEL);
    conv_silu_k<<<NROW * (D_INNER / 4) / 256, 256, 0, stream>>>(
        xz_bf, conv_w, conv_b, xc_bf);
    // xproj: 64x128 tile, split-K x8 (slice 192, BK=64) -> 256 blocks
    gemm_splitk<2, 4, 192><<<dim3(NROW / 64, 1, 8), 256, 0, stream>>>(
        xc_bf, Wxp_bf, xdbl, D_INNER, XDS);
    // dt: 2048x1536x64, bf16 out; 768 blocks
    dtgemm_k<<<dim3(NROW / 64, D_INNER / 64), 256, 0, stream>>>(
        xdbl, Wdt_bf, b_dt, dtbuf);

    scan_p1<<<2 * NCHUNK * D_INNER / 256, 256, 0, stream>>>(
        dtbuf, xc_bf, xdbl, negA, Sbuf, dtsumb);
    scan_p2<<<2 * D_INNER * D_STATE / 256, 256, 0, stream>>>(
        Sbuf, dtsumb, negA, carryb);
    scan_p3<<<2 * NCHUNK * D_INNER / 256, 256, 0, stream>>>(
        dtbuf, xc_bf, xz_bf, xdbl, negA, Dp, carryb, yybuf);

    // GEMM-out: 2048x768x1536, 64x64 tiles, BK=64 -> 384 blocks, fused +x
    gemm128<2, 2, false, true><<<dim3(NROW / 64, D_MODEL / 64), 256, 0, stream>>>(
        yybuf, Wout_bf, x, out, NROW, D_MODEL, D_INNER);
}